// Round 1
// baseline (565.480 us; speedup 1.0000x reference)
//
#include <hip/hip_runtime.h>

// ---------- bf16 helpers (manual bit conversion, RNE) ----------
__device__ __forceinline__ unsigned short f2bf(float f) {
    unsigned int x = __float_as_uint(f);
    x += 0x7fffu + ((x >> 16) & 1u);
    return (unsigned short)(x >> 16);
}
__device__ __forceinline__ float2 bf2x(unsigned int u) {
    // low ushort -> .x, high ushort -> .y
    float2 r;
    r.x = __uint_as_float(u << 16);
    r.y = __uint_as_float(u & 0xffff0000u);
    return r;
}

// ---------- Projection: out[r][c] = dot(in[r][:], W[c][:]) (+ b[c]), bf16 out
// One block = 32 rows x 128 cols, 3 weight matrices applied per block so the
// input tile is staged into LDS once. FP32 vector GEMM (no fp32 MFMA on CDNA4).
#define PROJ_ROWS 32
__global__ __launch_bounds__(256) void proj3(
    const float* __restrict__ in, int N,
    const float* __restrict__ W0, const float* __restrict__ b0, unsigned short* __restrict__ out0,
    const float* __restrict__ W1, const float* __restrict__ b1, unsigned short* __restrict__ out1,
    const float* __restrict__ W2, unsigned short* __restrict__ out2)
{
    // At[k][r]: input tile transposed, padded to 36 floats (144B: 16B-aligned rows,
    // read pattern is wave-uniform broadcast -> conflict-free).
    __shared__ __align__(16) float At[128][36];
    __shared__ __align__(16) float Wt[64][128];   // k-chunked transposed W

    const int tid = threadIdx.x;
    const int row0 = blockIdx.x * PROJ_ROWS;

    // ---- stage input tile (transposed) ----
    {
        const int r = tid >> 3;            // 0..31
        const int kb = (tid & 7) * 4;      // 0,4,...,28
        const bool valid = (row0 + r) < N;
        const float* src = in + (size_t)(row0 + r) * 128;
#pragma unroll
        for (int j = 0; j < 4; j++) {
            int k = kb + j * 32;
            float4 v = make_float4(0.f, 0.f, 0.f, 0.f);
            if (valid) v = *(const float4*)(src + k);
            At[k + 0][r] = v.x; At[k + 1][r] = v.y;
            At[k + 2][r] = v.z; At[k + 3][r] = v.w;
        }
    }

    const int tx = tid & 31;   // col group: cols 4*tx..4*tx+3
    const int ty = tid >> 5;   // row group: rows 4*ty..4*ty+3

    for (int w = 0; w < 3; w++) {
        const float* Wp = (w == 0) ? W0 : (w == 1) ? W1 : W2;
        float acc[4][4] = {};

        for (int kk = 0; kk < 128; kk += 64) {
            __syncthreads();   // protect Wt reuse (also covers At visibility 1st time)
            // stage Wt[k'][c] = W[c][kk+k']
            {
                const int c = tid >> 1;
                const int h = (tid & 1) * 32;
#pragma unroll
                for (int j = 0; j < 8; j++) {
                    int k = h + 4 * j;
                    float4 v = *(const float4*)(Wp + (size_t)c * 128 + kk + k);
                    Wt[k + 0][c] = v.x; Wt[k + 1][c] = v.y;
                    Wt[k + 2][c] = v.z; Wt[k + 3][c] = v.w;
                }
            }
            __syncthreads();
#pragma unroll 8
            for (int k = 0; k < 64; k++) {
                float4 a = *(const float4*)&At[kk + k][ty * 4];
                float4 b = *(const float4*)&Wt[k][tx * 4];
                float av[4] = {a.x, a.y, a.z, a.w};
                float bv[4] = {b.x, b.y, b.z, b.w};
#pragma unroll
                for (int i = 0; i < 4; i++)
#pragma unroll
                    for (int j = 0; j < 4; j++)
                        acc[i][j] = fmaf(av[i], bv[j], acc[i][j]);
            }
        }

        float4 bias = make_float4(0.f, 0.f, 0.f, 0.f);
        if (w == 0 && b0) bias = *(const float4*)(b0 + tx * 4);
        if (w == 1 && b1) bias = *(const float4*)(b1 + tx * 4);
        unsigned short* outp = (w == 0) ? out0 : (w == 1) ? out1 : out2;
        float bv[4] = {bias.x, bias.y, bias.z, bias.w};
#pragma unroll
        for (int i = 0; i < 4; i++) {
            int r = row0 + ty * 4 + i;
            if (r < N) {
                ushort4 u;
                u.x = f2bf(acc[i][0] + bv[0]);
                u.y = f2bf(acc[i][1] + bv[1]);
                u.z = f2bf(acc[i][2] + bv[2]);
                u.w = f2bf(acc[i][3] + bv[3]);
                *(ushort4*)(outp + (size_t)r * 128 + tx * 4) = u;
            }
        }
    }
}

// ---------- CSR build ----------
__global__ __launch_bounds__(256) void hist_k(const int* __restrict__ row, int* __restrict__ deg, int E) {
    int e = blockIdx.x * 256 + threadIdx.x;
    if (e < E) atomicAdd(&deg[row[e]], 1);
}

__global__ __launch_bounds__(1024) void scan_k(const int* __restrict__ deg,
                                               int* __restrict__ offs,
                                               int* __restrict__ cursor, int N) {
    __shared__ int lds[1024];
    const int tid = threadIdx.x;
    const int chunk = (N + 1023) >> 10;
    const int lo = tid * chunk;
    const int hi = min(lo + chunk, N);
    int s = 0;
    for (int i = lo; i < hi; i++) s += deg[i];
    lds[tid] = s;
    __syncthreads();
    for (int d = 1; d < 1024; d <<= 1) {
        int v = (tid >= d) ? lds[tid - d] : 0;
        __syncthreads();
        lds[tid] += v;
        __syncthreads();
    }
    int run = (tid == 0) ? 0 : lds[tid - 1];
    for (int i = lo; i < hi; i++) {
        offs[i] = run; cursor[i] = run; run += deg[i];
    }
    if (tid == 1023) offs[N] = lds[1023];
}

__global__ __launch_bounds__(256) void scatter_k(const int* __restrict__ row,
                                                 int* __restrict__ cursor,
                                                 int* __restrict__ csr, int E) {
    int e = blockIdx.x * 256 + threadIdx.x;
    if (e < E) {
        int p = atomicAdd(&cursor[row[e]], 1);
        csr[p] = e;
    }
}

// ---------- Edge scores: 16 lanes per edge ----------
__global__ __launch_bounds__(256) void edge_scores(
    const unsigned short* __restrict__ qa, const unsigned short* __restrict__ ka,
    const unsigned short* __restrict__ qb, const unsigned short* __restrict__ kb,
    const int* __restrict__ row, const int* __restrict__ col,
    float* __restrict__ sa, float* __restrict__ sb, int E)
{
    int g = blockIdx.x * 256 + threadIdx.x;
    int e = g >> 4;
    int l = g & 15;
    if (e >= E) return;
    int r = row[e], c = col[e];

    uint4 q0 = *(const uint4*)(qa + (size_t)r * 128 + l * 8);
    uint4 k0 = *(const uint4*)(ka + (size_t)c * 128 + l * 8);
    uint4 q1 = *(const uint4*)(qb + (size_t)r * 128 + l * 8);
    uint4 k1 = *(const uint4*)(kb + (size_t)c * 128 + l * 8);

    float pa = 0.f, pb = 0.f;
    {
        float2 a, b;
        a = bf2x(q0.x); b = bf2x(k0.x); pa = fmaf(a.x, b.x, fmaf(a.y, b.y, pa));
        a = bf2x(q0.y); b = bf2x(k0.y); pa = fmaf(a.x, b.x, fmaf(a.y, b.y, pa));
        a = bf2x(q0.z); b = bf2x(k0.z); pa = fmaf(a.x, b.x, fmaf(a.y, b.y, pa));
        a = bf2x(q0.w); b = bf2x(k0.w); pa = fmaf(a.x, b.x, fmaf(a.y, b.y, pa));
        a = bf2x(q1.x); b = bf2x(k1.x); pb = fmaf(a.x, b.x, fmaf(a.y, b.y, pb));
        a = bf2x(q1.y); b = bf2x(k1.y); pb = fmaf(a.x, b.x, fmaf(a.y, b.y, pb));
        a = bf2x(q1.z); b = bf2x(k1.z); pb = fmaf(a.x, b.x, fmaf(a.y, b.y, pb));
        a = bf2x(q1.w); b = bf2x(k1.w); pb = fmaf(a.x, b.x, fmaf(a.y, b.y, pb));
    }
#pragma unroll
    for (int off = 8; off; off >>= 1) {
        pa += __shfl_xor(pa, off, 64);
        pb += __shfl_xor(pb, off, 64);
    }
    if (l == 0) {
        const float s = 0.08838834764831845f;  // 1/sqrt(128)
        sa[e] = pa * s;
        sb[e] = pb * s;
    }
}

// ---------- Per-node softmax + aggregation: one wave per destination node ----------
__global__ __launch_bounds__(256) void node_aggregate(
    const float* __restrict__ sa, const float* __restrict__ sb,
    const unsigned short* __restrict__ tw, const unsigned short* __restrict__ xw,
    const int* __restrict__ col, const int* __restrict__ offs, const int* __restrict__ csr,
    float* __restrict__ out_x, float* __restrict__ out_t, int N)
{
    const int node = blockIdx.x * 4 + (threadIdx.x >> 6);
    if (node >= N) return;
    const int lane = threadIdx.x & 63;
    const int s = offs[node];
    const int epos_end = offs[node + 1];

    // pass 1: segment max then sum-exp (wave reduction)
    float ma = -INFINITY, mb = -INFINITY;
    for (int i = s + lane; i < epos_end; i += 64) {
        int e = csr[i];
        ma = fmaxf(ma, sa[e]);
        mb = fmaxf(mb, sb[e]);
    }
#pragma unroll
    for (int off = 32; off; off >>= 1) {
        ma = fmaxf(ma, __shfl_xor(ma, off, 64));
        mb = fmaxf(mb, __shfl_xor(mb, off, 64));
    }
    float da = 0.f, db = 0.f;
    for (int i = s + lane; i < epos_end; i += 64) {
        int e = csr[i];
        da += __expf(sa[e] - ma);
        db += __expf(sb[e] - mb);
    }
#pragma unroll
    for (int off = 32; off; off >>= 1) {
        da += __shfl_xor(da, off, 64);
        db += __shfl_xor(db, off, 64);
    }
    const float rda = (da > 0.f) ? 1.f / da : 0.f;
    const float rdb = (db > 0.f) ? 1.f / db : 0.f;

    // pass 2: weighted accumulation; lane owns dims 2*lane, 2*lane+1
    float acct0 = 0.f, acct1 = 0.f, accx0 = 0.f, accx1 = 0.f;
    for (int i = s; i < epos_end; i++) {
        int e = csr[i];
        int c = col[e];
        float wa = __expf(sa[e] - ma) * rda;
        float wb = __expf(sb[e] - mb) * rdb;
        float2 tf = bf2x(*(const unsigned int*)(tw + (size_t)c * 128 + lane * 2));
        float2 xf = bf2x(*(const unsigned int*)(xw + (size_t)c * 128 + lane * 2));
        acct0 = fmaf(wa, tf.x, acct0);
        acct1 = fmaf(wa, tf.y, acct1);
        accx0 = fmaf(wb, xf.x, accx0);
        accx1 = fmaf(wb, xf.y, accx1);
    }
    *(float2*)(out_x + (size_t)node * 128 + lane * 2) = make_float2(accx0, accx1);
    *(float2*)(out_t + (size_t)node * 128 + lane * 2) = make_float2(acct0, acct1);
}

extern "C" void kernel_launch(void* const* d_in, const int* in_sizes, int n_in,
                              void* d_out, int out_size, void* d_ws, size_t ws_size,
                              hipStream_t stream) {
    const float* x    = (const float*)d_in[0];
    const float* t    = (const float*)d_in[1];
    const int*   ei   = (const int*)d_in[2];
    const float* W_x  = (const float*)d_in[3];
    const float* W_t  = (const float*)d_in[4];
    const float* Qa_w = (const float*)d_in[5];
    const float* Qa_b = (const float*)d_in[6];
    const float* Ka_w = (const float*)d_in[7];
    const float* Ka_b = (const float*)d_in[8];
    const float* Qb_w = (const float*)d_in[9];
    const float* Qb_b = (const float*)d_in[10];
    const float* Kb_w = (const float*)d_in[11];
    const float* Kb_b = (const float*)d_in[12];

    const int N = in_sizes[0] / 128;
    const int E = in_sizes[2] / 2;
    const int* row = ei;
    const int* col = ei + E;

    char* ws = (char*)d_ws;
    size_t off = 0;
    auto carve = [&](size_t bytes) -> void* {
        void* p = ws + off;
        off += (bytes + 255) & ~(size_t)255;
        return p;
    };
    unsigned short* qa = (unsigned short*)carve((size_t)N * 128 * 2);
    unsigned short* ka = (unsigned short*)carve((size_t)N * 128 * 2);
    unsigned short* qb = (unsigned short*)carve((size_t)N * 128 * 2);
    unsigned short* kb = (unsigned short*)carve((size_t)N * 128 * 2);
    unsigned short* tw = (unsigned short*)carve((size_t)N * 128 * 2);
    unsigned short* xw = (unsigned short*)carve((size_t)N * 128 * 2);
    float* sa   = (float*)carve((size_t)E * 4);
    float* sb   = (float*)carve((size_t)E * 4);
    int* deg    = (int*)carve((size_t)N * 4);
    int* cursor = (int*)carve((size_t)N * 4);
    int* offs   = (int*)carve((size_t)(N + 1) * 4);
    int* csr    = (int*)carve((size_t)E * 4);

    hipMemsetAsync(deg, 0, (size_t)N * 4, stream);

    dim3 b256(256);
    proj3<<<dim3((N + PROJ_ROWS - 1) / PROJ_ROWS), b256, 0, stream>>>(
        t, N, Qa_w, Qa_b, qa, Ka_w, Ka_b, ka, W_t, tw);
    proj3<<<dim3((N + PROJ_ROWS - 1) / PROJ_ROWS), b256, 0, stream>>>(
        x, N, Qb_w, Qb_b, qb, Kb_w, Kb_b, kb, W_x, xw);
    hist_k<<<dim3((E + 255) / 256), b256, 0, stream>>>(row, deg, E);
    scan_k<<<dim3(1), dim3(1024), 0, stream>>>(deg, offs, cursor, N);
    scatter_k<<<dim3((E + 255) / 256), b256, 0, stream>>>(row, cursor, csr, E);
    edge_scores<<<dim3((E * 16 + 255) / 256), b256, 0, stream>>>(
        qa, ka, qb, kb, row, col, sa, sb, E);

    float* out_x = (float*)d_out;
    float* out_t = out_x + (size_t)N * 128;
    node_aggregate<<<dim3((N + 3) / 4), b256, 0, stream>>>(
        sa, sb, tw, xw, col, offs, csr, out_x, out_t, N);
}

// Round 2
// 465.689 us; speedup vs baseline: 1.2143x; 1.2143x over previous
//
#include <hip/hip_runtime.h>

// ---------- bf16 helpers (manual bit conversion, RNE) ----------
__device__ __forceinline__ unsigned short f2bf(float f) {
    unsigned int x = __float_as_uint(f);
    x += 0x7fffu + ((x >> 16) & 1u);
    return (unsigned short)(x >> 16);
}
__device__ __forceinline__ float2 bf2x(unsigned int u) {
    // low ushort -> .x, high ushort -> .y
    float2 r;
    r.x = __uint_as_float(u << 16);
    r.y = __uint_as_float(u & 0xffff0000u);
    return r;
}

// ---------- Projection: out[r][c] = dot(in[r][:], W[c][:]) (+ b[c]), bf16 out
#define PROJ_ROWS 32
__global__ __launch_bounds__(256) void proj3(
    const float* __restrict__ in, int N,
    const float* __restrict__ W0, const float* __restrict__ b0, unsigned short* __restrict__ out0,
    const float* __restrict__ W1, const float* __restrict__ b1, unsigned short* __restrict__ out1,
    const float* __restrict__ W2, unsigned short* __restrict__ out2)
{
    __shared__ __align__(16) float At[128][36];
    __shared__ __align__(16) float Wt[64][128];   // k-chunked transposed W

    const int tid = threadIdx.x;
    const int row0 = blockIdx.x * PROJ_ROWS;

    // ---- stage input tile (transposed) ----
    {
        const int r = tid >> 3;            // 0..31
        const int kb = (tid & 7) * 4;      // 0,4,...,28
        const bool valid = (row0 + r) < N;
        const float* src = in + (size_t)(row0 + r) * 128;
#pragma unroll
        for (int j = 0; j < 4; j++) {
            int k = kb + j * 32;
            float4 v = make_float4(0.f, 0.f, 0.f, 0.f);
            if (valid) v = *(const float4*)(src + k);
            At[k + 0][r] = v.x; At[k + 1][r] = v.y;
            At[k + 2][r] = v.z; At[k + 3][r] = v.w;
        }
    }

    const int tx = tid & 31;   // col group: cols 4*tx..4*tx+3
    const int ty = tid >> 5;   // row group: rows 4*ty..4*ty+3

    for (int w = 0; w < 3; w++) {
        const float* Wp = (w == 0) ? W0 : (w == 1) ? W1 : W2;
        float acc[4][4] = {};

        for (int kk = 0; kk < 128; kk += 64) {
            __syncthreads();
            // stage Wt[k'][c] = W[c][kk+k']
            {
                const int c = tid >> 1;
                const int h = (tid & 1) * 32;
#pragma unroll
                for (int j = 0; j < 8; j++) {
                    int k = h + 4 * j;
                    float4 v = *(const float4*)(Wp + (size_t)c * 128 + kk + k);
                    Wt[k + 0][c] = v.x; Wt[k + 1][c] = v.y;
                    Wt[k + 2][c] = v.z; Wt[k + 3][c] = v.w;
                }
            }
            __syncthreads();
#pragma unroll 8
            for (int k = 0; k < 64; k++) {
                float4 a = *(const float4*)&At[kk + k][ty * 4];
                float4 b = *(const float4*)&Wt[k][tx * 4];
                float av[4] = {a.x, a.y, a.z, a.w};
                float bv[4] = {b.x, b.y, b.z, b.w};
#pragma unroll
                for (int i = 0; i < 4; i++)
#pragma unroll
                    for (int j = 0; j < 4; j++)
                        acc[i][j] = fmaf(av[i], bv[j], acc[i][j]);
            }
        }

        float4 bias = make_float4(0.f, 0.f, 0.f, 0.f);
        if (w == 0 && b0) bias = *(const float4*)(b0 + tx * 4);
        if (w == 1 && b1) bias = *(const float4*)(b1 + tx * 4);
        unsigned short* outp = (w == 0) ? out0 : (w == 1) ? out1 : out2;
        float bv[4] = {bias.x, bias.y, bias.z, bias.w};
#pragma unroll
        for (int i = 0; i < 4; i++) {
            int r = row0 + ty * 4 + i;
            if (r < N) {
                ushort4 u;
                u.x = f2bf(acc[i][0] + bv[0]);
                u.y = f2bf(acc[i][1] + bv[1]);
                u.z = f2bf(acc[i][2] + bv[2]);
                u.w = f2bf(acc[i][3] + bv[3]);
                *(ushort4*)(outp + (size_t)r * 128 + tx * 4) = u;
            }
        }
    }
}

// ---------- CSR build ----------
__global__ __launch_bounds__(256) void hist_k(const int* __restrict__ row, int* __restrict__ deg, int E) {
    int e = blockIdx.x * 256 + threadIdx.x;
    if (e < E) atomicAdd(&deg[row[e]], 1);
}

// ---- device-wide scan over deg[0..N): 3 kernels, 2048 elems per block ----
#define SCAN_CHUNK 2048   // 256 threads x 8

__device__ __forceinline__ int wave_incl_scan(int v, int lane) {
#pragma unroll
    for (int d = 1; d < 64; d <<= 1) {
        int u = __shfl_up(v, d, 64);
        if (lane >= d) v += u;
    }
    return v;
}

__global__ __launch_bounds__(256) void scan_partial(const int* __restrict__ deg,
                                                    int* __restrict__ partial, int N) {
    const int tid = threadIdx.x;
    const int base = blockIdx.x * SCAN_CHUNK + tid * 8;
    int s = 0;
#pragma unroll
    for (int j = 0; j < 8; j++) {
        int i = base + j;
        s += (i < N) ? deg[i] : 0;
    }
    const int lane = tid & 63;
    s = wave_incl_scan(s, lane);
    __shared__ int wsum[4];
    if (lane == 63) wsum[tid >> 6] = s;
    __syncthreads();
    if (tid == 0) {
        int t = wsum[0] + wsum[1] + wsum[2] + wsum[3];
        partial[blockIdx.x] = t;
    }
}

__global__ __launch_bounds__(64) void scan_base(int* __restrict__ partial, int nb,
                                                int* __restrict__ offs, int N) {
    const int lane = threadIdx.x;
    int v = (lane < nb) ? partial[lane] : 0;
    int inc = wave_incl_scan(v, lane);
    if (lane < nb) partial[lane] = inc - v;       // exclusive base per block
    if (lane == 63) offs[N] = inc;                // grand total
}

__global__ __launch_bounds__(256) void scan_final(const int* __restrict__ deg,
                                                  const int* __restrict__ partial,
                                                  int* __restrict__ offs,
                                                  int* __restrict__ cursor, int N) {
    const int tid = threadIdx.x;
    const int lane = tid & 63;
    const int wv = tid >> 6;
    const int base = blockIdx.x * SCAN_CHUNK + tid * 8;
    int v[8];
    int s = 0;
#pragma unroll
    for (int j = 0; j < 8; j++) {
        int i = base + j;
        v[j] = (i < N) ? deg[i] : 0;
        s += v[j];
    }
    int incl = wave_incl_scan(s, lane);
    __shared__ int wsum[4];
    if (lane == 63) wsum[wv] = incl;
    __syncthreads();
    int wbase = 0;
#pragma unroll
    for (int w = 0; w < 4; w++) wbase += (w < wv) ? wsum[w] : 0;
    int run = partial[blockIdx.x] + wbase + incl - s;   // exclusive prefix for this thread
#pragma unroll
    for (int j = 0; j < 8; j++) {
        int i = base + j;
        if (i < N) { offs[i] = run; cursor[i] = run; }
        run += v[j];
    }
}

__global__ __launch_bounds__(256) void scatter_k(const int* __restrict__ row,
                                                 int* __restrict__ cursor,
                                                 int* __restrict__ csr, int E) {
    int e = blockIdx.x * 256 + threadIdx.x;
    if (e < E) {
        int p = atomicAdd(&cursor[row[e]], 1);
        csr[p] = e;
    }
}

// ---------- Edge scores: 16 lanes per edge ----------
__global__ __launch_bounds__(256) void edge_scores(
    const unsigned short* __restrict__ qa, const unsigned short* __restrict__ ka,
    const unsigned short* __restrict__ qb, const unsigned short* __restrict__ kb,
    const int* __restrict__ row, const int* __restrict__ col,
    float* __restrict__ sa, float* __restrict__ sb, int E)
{
    int g = blockIdx.x * 256 + threadIdx.x;
    int e = g >> 4;
    int l = g & 15;
    if (e >= E) return;
    int r = row[e], c = col[e];

    uint4 q0 = *(const uint4*)(qa + (size_t)r * 128 + l * 8);
    uint4 k0 = *(const uint4*)(ka + (size_t)c * 128 + l * 8);
    uint4 q1 = *(const uint4*)(qb + (size_t)r * 128 + l * 8);
    uint4 k1 = *(const uint4*)(kb + (size_t)c * 128 + l * 8);

    float pa = 0.f, pb = 0.f;
    {
        float2 a, b;
        a = bf2x(q0.x); b = bf2x(k0.x); pa = fmaf(a.x, b.x, fmaf(a.y, b.y, pa));
        a = bf2x(q0.y); b = bf2x(k0.y); pa = fmaf(a.x, b.x, fmaf(a.y, b.y, pa));
        a = bf2x(q0.z); b = bf2x(k0.z); pa = fmaf(a.x, b.x, fmaf(a.y, b.y, pa));
        a = bf2x(q0.w); b = bf2x(k0.w); pa = fmaf(a.x, b.x, fmaf(a.y, b.y, pa));
        a = bf2x(q1.x); b = bf2x(k1.x); pb = fmaf(a.x, b.x, fmaf(a.y, b.y, pb));
        a = bf2x(q1.y); b = bf2x(k1.y); pb = fmaf(a.x, b.x, fmaf(a.y, b.y, pb));
        a = bf2x(q1.z); b = bf2x(k1.z); pb = fmaf(a.x, b.x, fmaf(a.y, b.y, pb));
        a = bf2x(q1.w); b = bf2x(k1.w); pb = fmaf(a.x, b.x, fmaf(a.y, b.y, pb));
    }
#pragma unroll
    for (int off = 8; off; off >>= 1) {
        pa += __shfl_xor(pa, off, 64);
        pb += __shfl_xor(pb, off, 64);
    }
    if (l == 0) {
        const float s = 0.08838834764831845f;  // 1/sqrt(128)
        sa[e] = pa * s;
        sb[e] = pb * s;
    }
}

// ---------- Per-node softmax + aggregation: one wave per destination node ----------
__global__ __launch_bounds__(256) void node_aggregate(
    const float* __restrict__ sa, const float* __restrict__ sb,
    const unsigned short* __restrict__ tw, const unsigned short* __restrict__ xw,
    const int* __restrict__ col, const int* __restrict__ offs, const int* __restrict__ csr,
    float* __restrict__ out_x, float* __restrict__ out_t, int N)
{
    const int node = blockIdx.x * 4 + (threadIdx.x >> 6);
    if (node >= N) return;
    const int lane = threadIdx.x & 63;
    const int s = offs[node];
    const int epos_end = offs[node + 1];

    // pass 1: segment max then sum-exp (wave reduction)
    float ma = -INFINITY, mb = -INFINITY;
    for (int i = s + lane; i < epos_end; i += 64) {
        int e = csr[i];
        ma = fmaxf(ma, sa[e]);
        mb = fmaxf(mb, sb[e]);
    }
#pragma unroll
    for (int off = 32; off; off >>= 1) {
        ma = fmaxf(ma, __shfl_xor(ma, off, 64));
        mb = fmaxf(mb, __shfl_xor(mb, off, 64));
    }
    float da = 0.f, db = 0.f;
    for (int i = s + lane; i < epos_end; i += 64) {
        int e = csr[i];
        da += __expf(sa[e] - ma);
        db += __expf(sb[e] - mb);
    }
#pragma unroll
    for (int off = 32; off; off >>= 1) {
        da += __shfl_xor(da, off, 64);
        db += __shfl_xor(db, off, 64);
    }
    const float rda = (da > 0.f) ? 1.f / da : 0.f;
    const float rdb = (db > 0.f) ? 1.f / db : 0.f;

    // pass 2: weighted accumulation; lane owns dims 2*lane, 2*lane+1
    float acct0 = 0.f, acct1 = 0.f, accx0 = 0.f, accx1 = 0.f;
    for (int i = s; i < epos_end; i++) {
        int e = csr[i];
        int c = col[e];
        float wa = __expf(sa[e] - ma) * rda;
        float wb = __expf(sb[e] - mb) * rdb;
        float2 tf = bf2x(*(const unsigned int*)(tw + (size_t)c * 128 + lane * 2));
        float2 xf = bf2x(*(const unsigned int*)(xw + (size_t)c * 128 + lane * 2));
        acct0 = fmaf(wa, tf.x, acct0);
        acct1 = fmaf(wa, tf.y, acct1);
        accx0 = fmaf(wb, xf.x, accx0);
        accx1 = fmaf(wb, xf.y, accx1);
    }
    *(float2*)(out_x + (size_t)node * 128 + lane * 2) = make_float2(accx0, accx1);
    *(float2*)(out_t + (size_t)node * 128 + lane * 2) = make_float2(acct0, acct1);
}

extern "C" void kernel_launch(void* const* d_in, const int* in_sizes, int n_in,
                              void* d_out, int out_size, void* d_ws, size_t ws_size,
                              hipStream_t stream) {
    const float* x    = (const float*)d_in[0];
    const float* t    = (const float*)d_in[1];
    const int*   ei   = (const int*)d_in[2];
    const float* W_x  = (const float*)d_in[3];
    const float* W_t  = (const float*)d_in[4];
    const float* Qa_w = (const float*)d_in[5];
    const float* Qa_b = (const float*)d_in[6];
    const float* Ka_w = (const float*)d_in[7];
    const float* Ka_b = (const float*)d_in[8];
    const float* Qb_w = (const float*)d_in[9];
    const float* Qb_b = (const float*)d_in[10];
    const float* Kb_w = (const float*)d_in[11];
    const float* Kb_b = (const float*)d_in[12];

    const int N = in_sizes[0] / 128;
    const int E = in_sizes[2] / 2;
    const int* row = ei;
    const int* col = ei + E;

    char* ws = (char*)d_ws;
    size_t off = 0;
    auto carve = [&](size_t bytes) -> void* {
        void* p = ws + off;
        off += (bytes + 255) & ~(size_t)255;
        return p;
    };
    unsigned short* qa = (unsigned short*)carve((size_t)N * 128 * 2);
    unsigned short* ka = (unsigned short*)carve((size_t)N * 128 * 2);
    unsigned short* qb = (unsigned short*)carve((size_t)N * 128 * 2);
    unsigned short* kb = (unsigned short*)carve((size_t)N * 128 * 2);
    unsigned short* tw = (unsigned short*)carve((size_t)N * 128 * 2);
    unsigned short* xw = (unsigned short*)carve((size_t)N * 128 * 2);
    float* sa   = (float*)carve((size_t)E * 4);
    float* sb   = (float*)carve((size_t)E * 4);
    int* deg    = (int*)carve((size_t)N * 4);
    int* cursor = (int*)carve((size_t)N * 4);
    int* offs   = (int*)carve((size_t)(N + 1) * 4);
    int* csr    = (int*)carve((size_t)E * 4);
    const int nscan = (N + SCAN_CHUNK - 1) / SCAN_CHUNK;   // 25 for N=50000
    int* partial = (int*)carve((size_t)nscan * 4);

    hipMemsetAsync(deg, 0, (size_t)N * 4, stream);

    dim3 b256(256);
    proj3<<<dim3((N + PROJ_ROWS - 1) / PROJ_ROWS), b256, 0, stream>>>(
        t, N, Qa_w, Qa_b, qa, Ka_w, Ka_b, ka, W_t, tw);
    proj3<<<dim3((N + PROJ_ROWS - 1) / PROJ_ROWS), b256, 0, stream>>>(
        x, N, Qb_w, Qb_b, qb, Kb_w, Kb_b, kb, W_x, xw);
    hist_k<<<dim3((E + 255) / 256), b256, 0, stream>>>(row, deg, E);
    scan_partial<<<dim3(nscan), b256, 0, stream>>>(deg, partial, N);
    scan_base<<<dim3(1), dim3(64), 0, stream>>>(partial, nscan, offs, N);
    scan_final<<<dim3(nscan), b256, 0, stream>>>(deg, partial, offs, cursor, N);
    scatter_k<<<dim3((E + 255) / 256), b256, 0, stream>>>(row, cursor, csr, E);
    edge_scores<<<dim3((E * 16 + 255) / 256), b256, 0, stream>>>(
        qa, ka, qb, kb, row, col, sa, sb, E);

    float* out_x = (float*)d_out;
    float* out_t = out_x + (size_t)N * 128;
    node_aggregate<<<dim3((N + 3) / 4), b256, 0, stream>>>(
        sa, sb, tw, xw, col, offs, csr, out_x, out_t, N);
}

// Round 3
// 410.671 us; speedup vs baseline: 1.3770x; 1.1340x over previous
//
#include <hip/hip_runtime.h>

// ---------- bf16 helpers (manual bit conversion, RNE) ----------
__device__ __forceinline__ unsigned short f2bf(float f) {
    unsigned int x = __float_as_uint(f);
    x += 0x7fffu + ((x >> 16) & 1u);
    return (unsigned short)(x >> 16);
}
__device__ __forceinline__ float2 bf2x(unsigned int u) {
    // low ushort -> .x, high ushort -> .y
    float2 r;
    r.x = __uint_as_float(u << 16);
    r.y = __uint_as_float(u & 0xffff0000u);
    return r;
}

typedef __attribute__((ext_vector_type(8))) short frag8;   // 8 bf16 (4 VGPRs)
typedef __attribute__((ext_vector_type(4))) float fragf4;  // 4 fp32 acc

// ---------- convert 6 weight matrices [128x128] fp32 -> bf16 ----------
__global__ __launch_bounds__(256) void convert_w(
    const float* __restrict__ s0, const float* __restrict__ s1,
    const float* __restrict__ s2, const float* __restrict__ s3,
    const float* __restrict__ s4, const float* __restrict__ s5,
    unsigned short* __restrict__ dst)
{
    int id = blockIdx.x * 256 + threadIdx.x;      // 96 blocks * 256 = 6*4096
    int m = id >> 12;
    int i = (id & 4095) * 4;
    const float* s = (m == 0) ? s0 : (m == 1) ? s1 : (m == 2) ? s2
                   : (m == 3) ? s3 : (m == 4) ? s4 : s5;
    float4 v = *(const float4*)(s + i);
    ushort4 u;
    u.x = f2bf(v.x); u.y = f2bf(v.y); u.z = f2bf(v.z); u.w = f2bf(v.w);
    *(ushort4*)(dst + m * 16384 + i) = u;
}

// ---------- MFMA projection: out[r][c] = dot(in[r][:], W[c][:]) (+ b[c])
// Block = 4 waves x 16 rows = 64 rows, all 128 output channels.
// A-operand = W (bf16, pre-converted), B-operand = input rows (fp32 -> bf16
// in registers, loaded ONCE and reused across all 3 weight matrices).
// MFMA 16x16x32: A[m=lane&15][k=quad*8+j], B[n=lane&15][k=quad*8+j],
// D: n(col)=lane&15 -> node row, m(row)=quad*4+reg -> 4 consecutive channels.
__global__ __launch_bounds__(256) void proj_mfma(
    const float* __restrict__ in, int N,
    const unsigned short* __restrict__ W0, const float* __restrict__ b0, unsigned short* __restrict__ out0,
    const unsigned short* __restrict__ W1, const float* __restrict__ b1, unsigned short* __restrict__ out1,
    const unsigned short* __restrict__ W2, unsigned short* __restrict__ out2)
{
    const int wave = threadIdx.x >> 6;
    const int lane = threadIdx.x & 63;
    const int li = lane & 15;      // row / channel index within tile
    const int quad = lane >> 4;    // 0..3
    const int r = blockIdx.x * 64 + wave * 16 + li;
    const bool rv = r < N;

    // ---- load this wave's 16 input rows as 4 K-step B fragments ----
    frag8 bfrag[4];
    {
        const float* src = in + (size_t)r * 128 + quad * 8;
#pragma unroll
        for (int ks = 0; ks < 4; ks++) {
            float4 lo = make_float4(0.f, 0.f, 0.f, 0.f);
            float4 hi = lo;
            if (rv) {
                lo = *(const float4*)(src + ks * 32);
                hi = *(const float4*)(src + ks * 32 + 4);
            }
            frag8 f;
            f[0] = (short)f2bf(lo.x); f[1] = (short)f2bf(lo.y);
            f[2] = (short)f2bf(lo.z); f[3] = (short)f2bf(lo.w);
            f[4] = (short)f2bf(hi.x); f[5] = (short)f2bf(hi.y);
            f[6] = (short)f2bf(hi.z); f[7] = (short)f2bf(hi.w);
            bfrag[ks] = f;
        }
    }

#pragma unroll 1
    for (int w = 0; w < 3; w++) {
        const unsigned short* Wb = (w == 0) ? W0 : (w == 1) ? W1 : W2;
        const float* bias = (w == 0) ? b0 : (w == 1) ? b1 : nullptr;
        unsigned short* outp = (w == 0) ? out0 : (w == 1) ? out1 : out2;

        fragf4 acc[8];
#pragma unroll
        for (int ct = 0; ct < 8; ct++) acc[ct] = (fragf4){0.f, 0.f, 0.f, 0.f};

#pragma unroll
        for (int ct = 0; ct < 8; ct++) {
            const unsigned short* wp = Wb + (size_t)(ct * 16 + li) * 128 + quad * 8;
#pragma unroll
            for (int ks = 0; ks < 4; ks++) {
                frag8 af = *(const frag8*)(wp + ks * 32);
                acc[ct] = __builtin_amdgcn_mfma_f32_16x16x32_bf16(af, bfrag[ks], acc[ct], 0, 0, 0);
            }
        }

        if (rv) {
#pragma unroll
            for (int ct = 0; ct < 8; ct++) {
                const int c = ct * 16 + quad * 4;
                float4 bv = make_float4(0.f, 0.f, 0.f, 0.f);
                if (bias) bv = *(const float4*)(bias + c);
                ushort4 u;
                u.x = f2bf(acc[ct][0] + bv.x);
                u.y = f2bf(acc[ct][1] + bv.y);
                u.z = f2bf(acc[ct][2] + bv.z);
                u.w = f2bf(acc[ct][3] + bv.w);
                *(ushort4*)(outp + (size_t)r * 128 + c) = u;
            }
        }
    }
}

// ---------- CSR build ----------
__global__ __launch_bounds__(256) void hist_k(const int* __restrict__ row, int* __restrict__ deg, int E) {
    int e = blockIdx.x * 256 + threadIdx.x;
    if (e < E) atomicAdd(&deg[row[e]], 1);
}

// ---- device-wide scan over deg[0..N): 3 kernels, 2048 elems per block ----
#define SCAN_CHUNK 2048   // 256 threads x 8

__device__ __forceinline__ int wave_incl_scan(int v, int lane) {
#pragma unroll
    for (int d = 1; d < 64; d <<= 1) {
        int u = __shfl_up(v, d, 64);
        if (lane >= d) v += u;
    }
    return v;
}

__global__ __launch_bounds__(256) void scan_partial(const int* __restrict__ deg,
                                                    int* __restrict__ partial, int N) {
    const int tid = threadIdx.x;
    const int base = blockIdx.x * SCAN_CHUNK + tid * 8;
    int s = 0;
#pragma unroll
    for (int j = 0; j < 8; j++) {
        int i = base + j;
        s += (i < N) ? deg[i] : 0;
    }
    const int lane = tid & 63;
    s = wave_incl_scan(s, lane);
    __shared__ int wsum[4];
    if (lane == 63) wsum[tid >> 6] = s;
    __syncthreads();
    if (tid == 0) {
        int t = wsum[0] + wsum[1] + wsum[2] + wsum[3];
        partial[blockIdx.x] = t;
    }
}

__global__ __launch_bounds__(64) void scan_base(int* __restrict__ partial, int nb,
                                                int* __restrict__ offs, int N) {
    const int lane = threadIdx.x;
    int v = (lane < nb) ? partial[lane] : 0;
    int inc = wave_incl_scan(v, lane);
    if (lane < nb) partial[lane] = inc - v;       // exclusive base per block
    if (lane == 63) offs[N] = inc;                // grand total
}

__global__ __launch_bounds__(256) void scan_final(const int* __restrict__ deg,
                                                  const int* __restrict__ partial,
                                                  int* __restrict__ offs,
                                                  int* __restrict__ cursor, int N) {
    const int tid = threadIdx.x;
    const int lane = tid & 63;
    const int wv = tid >> 6;
    const int base = blockIdx.x * SCAN_CHUNK + tid * 8;
    int v[8];
    int s = 0;
#pragma unroll
    for (int j = 0; j < 8; j++) {
        int i = base + j;
        v[j] = (i < N) ? deg[i] : 0;
        s += v[j];
    }
    int incl = wave_incl_scan(s, lane);
    __shared__ int wsum[4];
    if (lane == 63) wsum[wv] = incl;
    __syncthreads();
    int wbase = 0;
#pragma unroll
    for (int w = 0; w < 4; w++) wbase += (w < wv) ? wsum[w] : 0;
    int run = partial[blockIdx.x] + wbase + incl - s;   // exclusive prefix for this thread
#pragma unroll
    for (int j = 0; j < 8; j++) {
        int i = base + j;
        if (i < N) { offs[i] = run; cursor[i] = run; }
        run += v[j];
    }
}

__global__ __launch_bounds__(256) void scatter_k(const int* __restrict__ row,
                                                 int* __restrict__ cursor,
                                                 int* __restrict__ csr, int E) {
    int e = blockIdx.x * 256 + threadIdx.x;
    if (e < E) {
        int p = atomicAdd(&cursor[row[e]], 1);
        csr[p] = e;
    }
}

// ---------- Edge scores: 16 lanes per edge ----------
__global__ __launch_bounds__(256) void edge_scores(
    const unsigned short* __restrict__ qa, const unsigned short* __restrict__ ka,
    const unsigned short* __restrict__ qb, const unsigned short* __restrict__ kb,
    const int* __restrict__ row, const int* __restrict__ col,
    float* __restrict__ sa, float* __restrict__ sb, int E)
{
    int g = blockIdx.x * 256 + threadIdx.x;
    int e = g >> 4;
    int l = g & 15;
    if (e >= E) return;
    int r = row[e], c = col[e];

    uint4 q0 = *(const uint4*)(qa + (size_t)r * 128 + l * 8);
    uint4 k0 = *(const uint4*)(ka + (size_t)c * 128 + l * 8);
    uint4 q1 = *(const uint4*)(qb + (size_t)r * 128 + l * 8);
    uint4 k1 = *(const uint4*)(kb + (size_t)c * 128 + l * 8);

    float pa = 0.f, pb = 0.f;
    {
        float2 a, b;
        a = bf2x(q0.x); b = bf2x(k0.x); pa = fmaf(a.x, b.x, fmaf(a.y, b.y, pa));
        a = bf2x(q0.y); b = bf2x(k0.y); pa = fmaf(a.x, b.x, fmaf(a.y, b.y, pa));
        a = bf2x(q0.z); b = bf2x(k0.z); pa = fmaf(a.x, b.x, fmaf(a.y, b.y, pa));
        a = bf2x(q0.w); b = bf2x(k0.w); pa = fmaf(a.x, b.x, fmaf(a.y, b.y, pa));
        a = bf2x(q1.x); b = bf2x(k1.x); pb = fmaf(a.x, b.x, fmaf(a.y, b.y, pb));
        a = bf2x(q1.y); b = bf2x(k1.y); pb = fmaf(a.x, b.x, fmaf(a.y, b.y, pb));
        a = bf2x(q1.z); b = bf2x(k1.z); pb = fmaf(a.x, b.x, fmaf(a.y, b.y, pb));
        a = bf2x(q1.w); b = bf2x(k1.w); pb = fmaf(a.x, b.x, fmaf(a.y, b.y, pb));
    }
#pragma unroll
    for (int off = 8; off; off >>= 1) {
        pa += __shfl_xor(pa, off, 64);
        pb += __shfl_xor(pb, off, 64);
    }
    if (l == 0) {
        const float s = 0.08838834764831845f;  // 1/sqrt(128)
        sa[e] = pa * s;
        sb[e] = pb * s;
    }
}

// ---------- Per-node softmax + aggregation: one wave per destination node ----------
__global__ __launch_bounds__(256) void node_aggregate(
    const float* __restrict__ sa, const float* __restrict__ sb,
    const unsigned short* __restrict__ tw, const unsigned short* __restrict__ xw,
    const int* __restrict__ col, const int* __restrict__ offs, const int* __restrict__ csr,
    float* __restrict__ out_x, float* __restrict__ out_t, int N)
{
    const int node = blockIdx.x * 4 + (threadIdx.x >> 6);
    if (node >= N) return;
    const int lane = threadIdx.x & 63;
    const int s = offs[node];
    const int epos_end = offs[node + 1];

    // pass 1: segment max then sum-exp (wave reduction)
    float ma = -INFINITY, mb = -INFINITY;
    for (int i = s + lane; i < epos_end; i += 64) {
        int e = csr[i];
        ma = fmaxf(ma, sa[e]);
        mb = fmaxf(mb, sb[e]);
    }
#pragma unroll
    for (int off = 32; off; off >>= 1) {
        ma = fmaxf(ma, __shfl_xor(ma, off, 64));
        mb = fmaxf(mb, __shfl_xor(mb, off, 64));
    }
    float da = 0.f, db = 0.f;
    for (int i = s + lane; i < epos_end; i += 64) {
        int e = csr[i];
        da += __expf(sa[e] - ma);
        db += __expf(sb[e] - mb);
    }
#pragma unroll
    for (int off = 32; off; off >>= 1) {
        da += __shfl_xor(da, off, 64);
        db += __shfl_xor(db, off, 64);
    }
    const float rda = (da > 0.f) ? 1.f / da : 0.f;
    const float rdb = (db > 0.f) ? 1.f / db : 0.f;

    // pass 2: weighted accumulation; lane owns dims 2*lane, 2*lane+1
    float acct0 = 0.f, acct1 = 0.f, accx0 = 0.f, accx1 = 0.f;
    for (int i = s; i < epos_end; i++) {
        int e = csr[i];
        int c = col[e];
        float wa = __expf(sa[e] - ma) * rda;
        float wb = __expf(sb[e] - mb) * rdb;
        float2 tf = bf2x(*(const unsigned int*)(tw + (size_t)c * 128 + lane * 2));
        float2 xf = bf2x(*(const unsigned int*)(xw + (size_t)c * 128 + lane * 2));
        acct0 = fmaf(wa, tf.x, acct0);
        acct1 = fmaf(wa, tf.y, acct1);
        accx0 = fmaf(wb, xf.x, accx0);
        accx1 = fmaf(wb, xf.y, accx1);
    }
    *(float2*)(out_x + (size_t)node * 128 + lane * 2) = make_float2(accx0, accx1);
    *(float2*)(out_t + (size_t)node * 128 + lane * 2) = make_float2(acct0, acct1);
}

extern "C" void kernel_launch(void* const* d_in, const int* in_sizes, int n_in,
                              void* d_out, int out_size, void* d_ws, size_t ws_size,
                              hipStream_t stream) {
    const float* x    = (const float*)d_in[0];
    const float* t    = (const float*)d_in[1];
    const int*   ei   = (const int*)d_in[2];
    const float* W_x  = (const float*)d_in[3];
    const float* W_t  = (const float*)d_in[4];
    const float* Qa_w = (const float*)d_in[5];
    const float* Qa_b = (const float*)d_in[6];
    const float* Ka_w = (const float*)d_in[7];
    const float* Ka_b = (const float*)d_in[8];
    const float* Qb_w = (const float*)d_in[9];
    const float* Qb_b = (const float*)d_in[10];
    const float* Kb_w = (const float*)d_in[11];
    const float* Kb_b = (const float*)d_in[12];

    const int N = in_sizes[0] / 128;
    const int E = in_sizes[2] / 2;
    const int* row = ei;
    const int* col = ei + E;

    char* ws = (char*)d_ws;
    size_t off = 0;
    auto carve = [&](size_t bytes) -> void* {
        void* p = ws + off;
        off += (bytes + 255) & ~(size_t)255;
        return p;
    };
    unsigned short* qa = (unsigned short*)carve((size_t)N * 128 * 2);
    unsigned short* ka = (unsigned short*)carve((size_t)N * 128 * 2);
    unsigned short* qb = (unsigned short*)carve((size_t)N * 128 * 2);
    unsigned short* kb = (unsigned short*)carve((size_t)N * 128 * 2);
    unsigned short* tw = (unsigned short*)carve((size_t)N * 128 * 2);
    unsigned short* xw = (unsigned short*)carve((size_t)N * 128 * 2);
    float* sa   = (float*)carve((size_t)E * 4);
    float* sb   = (float*)carve((size_t)E * 4);
    int* deg    = (int*)carve((size_t)N * 4);
    int* cursor = (int*)carve((size_t)N * 4);
    int* offs   = (int*)carve((size_t)(N + 1) * 4);
    int* csr    = (int*)carve((size_t)E * 4);
    const int nscan = (N + SCAN_CHUNK - 1) / SCAN_CHUNK;   // 25 for N=50000
    int* partial = (int*)carve((size_t)nscan * 4);
    unsigned short* Wbf = (unsigned short*)carve((size_t)6 * 16384 * 2);

    hipMemsetAsync(deg, 0, (size_t)N * 4, stream);

    dim3 b256(256);
    // weight order: [Qa_w, Ka_w, W_t, Qb_w, Kb_w, W_x]
    convert_w<<<dim3(96), b256, 0, stream>>>(Qa_w, Ka_w, W_t, Qb_w, Kb_w, W_x, Wbf);

    const int pgrid = (N + 63) / 64;
    proj_mfma<<<dim3(pgrid), b256, 0, stream>>>(
        t, N, Wbf + 0 * 16384, Qa_b, qa, Wbf + 1 * 16384, Ka_b, ka, Wbf + 2 * 16384, tw);
    proj_mfma<<<dim3(pgrid), b256, 0, stream>>>(
        x, N, Wbf + 3 * 16384, Qb_b, qb, Wbf + 4 * 16384, Kb_b, kb, Wbf + 5 * 16384, xw);

    hist_k<<<dim3((E + 255) / 256), b256, 0, stream>>>(row, deg, E);
    scan_partial<<<dim3(nscan), b256, 0, stream>>>(deg, partial, N);
    scan_base<<<dim3(1), dim3(64), 0, stream>>>(partial, nscan, offs, N);
    scan_final<<<dim3(nscan), b256, 0, stream>>>(deg, partial, offs, cursor, N);
    scatter_k<<<dim3((E + 255) / 256), b256, 0, stream>>>(row, cursor, csr, E);
    edge_scores<<<dim3((E * 16 + 255) / 256), b256, 0, stream>>>(
        qa, ka, qb, kb, row, col, sa, sb, E);

    float* out_x = (float*)d_out;
    float* out_t = out_x + (size_t)N * 128;
    node_aggregate<<<dim3((N + 3) / 4), b256, 0, stream>>>(
        sa, sb, tw, xw, col, offs, csr, out_x, out_t, N);
}

// Round 4
// 367.309 us; speedup vs baseline: 1.5395x; 1.1181x over previous
//
#include <hip/hip_runtime.h>

// ---------- bf16 helpers ----------
__device__ __forceinline__ unsigned short f2bf(float f) {
    unsigned int x = __float_as_uint(f);
    x += 0x7fffu + ((x >> 16) & 1u);
    return (unsigned short)(x >> 16);
}
__device__ __forceinline__ float2 bf2x(unsigned int u) {
    float2 r;
    r.x = __uint_as_float(u << 16);
    r.y = __uint_as_float(u & 0xffff0000u);
    return r;
}

typedef __attribute__((ext_vector_type(8))) short frag8;   // 8 bf16
typedef __attribute__((ext_vector_type(4))) float fragf4;  // 4 fp32 acc

// ---------- convert 6 weight matrices [128x128] fp32 -> bf16 ----------
__global__ __launch_bounds__(256) void convert_w(
    const float* __restrict__ s0, const float* __restrict__ s1,
    const float* __restrict__ s2, const float* __restrict__ s3,
    const float* __restrict__ s4, const float* __restrict__ s5,
    unsigned short* __restrict__ dst)
{
    int id = blockIdx.x * 256 + threadIdx.x;
    int m = id >> 12;
    int i = (id & 4095) * 4;
    const float* s = (m == 0) ? s0 : (m == 1) ? s1 : (m == 2) ? s2
                   : (m == 3) ? s3 : (m == 4) ? s4 : s5;
    float4 v = *(const float4*)(s + i);
    ushort4 u;
    u.x = f2bf(v.x); u.y = f2bf(v.y); u.z = f2bf(v.z); u.w = f2bf(v.w);
    *(ushort4*)(dst + m * 16384 + i) = u;
}

// ---------- MFMA projection with 3 output layouts ----------
// out0: plain [N][128] (q-rows). out1: kab chunk-interleave:
//   node row of 256 ushorts; dims [8q..8q+8) of ka at q*16+kab_off (+0 or +8).
// out2: twxw pair-interleave: dims (2p,2p+1) of tw at p*4+twxw_off (+0 or +2).
__global__ __launch_bounds__(256) void proj_mfma(
    const float* __restrict__ in, int N,
    const unsigned short* __restrict__ W0, const float* __restrict__ b0, unsigned short* __restrict__ out0,
    const unsigned short* __restrict__ W1, const float* __restrict__ b1, unsigned short* __restrict__ out1, int kab_off,
    const unsigned short* __restrict__ W2, unsigned short* __restrict__ out2, int twxw_off)
{
    const int wave = threadIdx.x >> 6;
    const int lane = threadIdx.x & 63;
    const int li = lane & 15;      // node row within tile (D col)
    const int quad = lane >> 4;    // 0..3
    const int r = blockIdx.x * 64 + wave * 16 + li;
    const bool rv = r < N;

    frag8 bfrag[4];
    {
        const float* src = in + (size_t)r * 128 + quad * 8;
#pragma unroll
        for (int ks = 0; ks < 4; ks++) {
            float4 lo = make_float4(0.f, 0.f, 0.f, 0.f);
            float4 hi = lo;
            if (rv) {
                lo = *(const float4*)(src + ks * 32);
                hi = *(const float4*)(src + ks * 32 + 4);
            }
            frag8 f;
            f[0] = (short)f2bf(lo.x); f[1] = (short)f2bf(lo.y);
            f[2] = (short)f2bf(lo.z); f[3] = (short)f2bf(lo.w);
            f[4] = (short)f2bf(hi.x); f[5] = (short)f2bf(hi.y);
            f[6] = (short)f2bf(hi.z); f[7] = (short)f2bf(hi.w);
            bfrag[ks] = f;
        }
    }

#pragma unroll 1
    for (int w = 0; w < 3; w++) {
        const unsigned short* Wb = (w == 0) ? W0 : (w == 1) ? W1 : W2;
        const float* bias = (w == 0) ? b0 : (w == 1) ? b1 : nullptr;

        fragf4 acc[8];
#pragma unroll
        for (int ct = 0; ct < 8; ct++) acc[ct] = (fragf4){0.f, 0.f, 0.f, 0.f};

#pragma unroll
        for (int ct = 0; ct < 8; ct++) {
            const unsigned short* wp = Wb + (size_t)(ct * 16 + li) * 128 + quad * 8;
#pragma unroll
            for (int ks = 0; ks < 4; ks++) {
                frag8 af = *(const frag8*)(wp + ks * 32);
                acc[ct] = __builtin_amdgcn_mfma_f32_16x16x32_bf16(af, bfrag[ks], acc[ct], 0, 0, 0);
            }
        }

        if (rv) {
#pragma unroll
            for (int ct = 0; ct < 8; ct++) {
                const int c = ct * 16 + quad * 4;
                float4 bv = make_float4(0.f, 0.f, 0.f, 0.f);
                if (bias) bv = *(const float4*)(bias + c);
                ushort4 u;
                u.x = f2bf(acc[ct][0] + bv.x);
                u.y = f2bf(acc[ct][1] + bv.y);
                u.z = f2bf(acc[ct][2] + bv.z);
                u.w = f2bf(acc[ct][3] + bv.w);
                if (w == 0) {
                    *(ushort4*)(out0 + (size_t)r * 128 + c) = u;
                } else if (w == 1) {
                    *(ushort4*)(out1 + (size_t)r * 256 + ((c >> 3) << 4) + kab_off + (c & 7)) = u;
                } else {
                    ushort2 p0; p0.x = u.x; p0.y = u.y;
                    ushort2 p1; p1.x = u.z; p1.y = u.w;
                    *(ushort2*)(out2 + (size_t)r * 256 + c * 2 + twxw_off) = p0;
                    *(ushort2*)(out2 + (size_t)r * 256 + c * 2 + 4 + twxw_off) = p1;
                }
            }
        }
    }
}

// ---------- CSR build ----------
__global__ __launch_bounds__(256) void hist_k(const int* __restrict__ row, int* __restrict__ deg, int E) {
    int e = blockIdx.x * 256 + threadIdx.x;
    if (e < E) atomicAdd(&deg[row[e]], 1);
}

#define SCAN_CHUNK 2048   // 256 threads x 8

__device__ __forceinline__ int wave_incl_scan(int v, int lane) {
#pragma unroll
    for (int d = 1; d < 64; d <<= 1) {
        int u = __shfl_up(v, d, 64);
        if (lane >= d) v += u;
    }
    return v;
}

__global__ __launch_bounds__(256) void scan_partial(const int* __restrict__ deg,
                                                    int* __restrict__ partial, int N) {
    const int tid = threadIdx.x;
    const int base = blockIdx.x * SCAN_CHUNK + tid * 8;
    int s = 0;
#pragma unroll
    for (int j = 0; j < 8; j++) {
        int i = base + j;
        s += (i < N) ? deg[i] : 0;
    }
    const int lane = tid & 63;
    s = wave_incl_scan(s, lane);
    __shared__ int wsum[4];
    if (lane == 63) wsum[tid >> 6] = s;
    __syncthreads();
    if (tid == 0) partial[blockIdx.x] = wsum[0] + wsum[1] + wsum[2] + wsum[3];
}

__global__ __launch_bounds__(64) void scan_base(int* __restrict__ partial, int nb,
                                                int* __restrict__ offs, int N) {
    const int lane = threadIdx.x;
    int v = (lane < nb) ? partial[lane] : 0;
    int inc = wave_incl_scan(v, lane);
    if (lane < nb) partial[lane] = inc - v;
    if (lane == 63) offs[N] = inc;
}

__global__ __launch_bounds__(256) void scan_final(const int* __restrict__ deg,
                                                  const int* __restrict__ partial,
                                                  int* __restrict__ offs,
                                                  int* __restrict__ cursor, int N) {
    const int tid = threadIdx.x;
    const int lane = tid & 63;
    const int wv = tid >> 6;
    const int base = blockIdx.x * SCAN_CHUNK + tid * 8;
    int v[8];
    int s = 0;
#pragma unroll
    for (int j = 0; j < 8; j++) {
        int i = base + j;
        v[j] = (i < N) ? deg[i] : 0;
        s += v[j];
    }
    int incl = wave_incl_scan(s, lane);
    __shared__ int wsum[4];
    if (lane == 63) wsum[wv] = incl;
    __syncthreads();
    int wbase = 0;
#pragma unroll
    for (int w = 0; w < 4; w++) wbase += (w < wv) ? wsum[w] : 0;
    int run = partial[blockIdx.x] + wbase + incl - s;
#pragma unroll
    for (int j = 0; j < 8; j++) {
        int i = base + j;
        if (i < N) { offs[i] = run; cursor[i] = run; }
        run += v[j];
    }
}

// scatter: write col (not edge id) into CSR slot — removes one indirection later
__global__ __launch_bounds__(256) void scatter_k(const int* __restrict__ row,
                                                 const int* __restrict__ col,
                                                 int* __restrict__ cursor,
                                                 int* __restrict__ csr_col, int E) {
    int e = blockIdx.x * 256 + threadIdx.x;
    if (e < E) {
        int p = atomicAdd(&cursor[row[e]], 1);
        csr_col[p] = col[e];
    }
}

// ---------- Edge scores in CSR order + fused online softmax stats ----------
// One wave per dest node; 4 edges x 16 lanes. q-rows register-resident.
__global__ __launch_bounds__(256) void edge_scores_csr(
    const unsigned short* __restrict__ qa, const unsigned short* __restrict__ qb,
    const unsigned short* __restrict__ kab,
    const int* __restrict__ csr_col, const int* __restrict__ offs,
    float2* __restrict__ s2, float4* __restrict__ params, int N)
{
    const int n = blockIdx.x * 4 + (threadIdx.x >> 6);
    if (n >= N) return;
    const int lane = threadIdx.x & 63;
    const int g = lane >> 4, sub = lane & 15;
    const int s = offs[n], e_end = offs[n + 1];

    float qaf[8], qbf[8];
    {
        uint4 a = *(const uint4*)(qa + (size_t)n * 128 + sub * 8);
        uint4 b = *(const uint4*)(qb + (size_t)n * 128 + sub * 8);
        float2 f;
        f = bf2x(a.x); qaf[0] = f.x; qaf[1] = f.y;
        f = bf2x(a.y); qaf[2] = f.x; qaf[3] = f.y;
        f = bf2x(a.z); qaf[4] = f.x; qaf[5] = f.y;
        f = bf2x(a.w); qaf[6] = f.x; qaf[7] = f.y;
        f = bf2x(b.x); qbf[0] = f.x; qbf[1] = f.y;
        f = bf2x(b.y); qbf[2] = f.x; qbf[3] = f.y;
        f = bf2x(b.z); qbf[4] = f.x; qbf[5] = f.y;
        f = bf2x(b.w); qbf[6] = f.x; qbf[7] = f.y;
    }

    const float NEG = -1e30f;
    const float scale = 0.08838834764831845f;  // 1/sqrt(128)
    float ma = NEG, da = 0.f, mb = NEG, db = 0.f;

    for (int i0 = s; i0 < e_end; i0 += 4) {
        const int i = i0 + g;
        const bool v = i < e_end;
        const int c = csr_col[v ? i : (e_end - 1)];
        const unsigned short* kp = kab + (size_t)c * 256 + sub * 16;
        uint4 ka4 = *(const uint4*)kp;
        uint4 kb4 = *(const uint4*)(kp + 8);
        float pa = 0.f, pb = 0.f;
        {
            float2 f;
            f = bf2x(ka4.x); pa = fmaf(qaf[0], f.x, fmaf(qaf[1], f.y, pa));
            f = bf2x(ka4.y); pa = fmaf(qaf[2], f.x, fmaf(qaf[3], f.y, pa));
            f = bf2x(ka4.z); pa = fmaf(qaf[4], f.x, fmaf(qaf[5], f.y, pa));
            f = bf2x(ka4.w); pa = fmaf(qaf[6], f.x, fmaf(qaf[7], f.y, pa));
            f = bf2x(kb4.x); pb = fmaf(qbf[0], f.x, fmaf(qbf[1], f.y, pb));
            f = bf2x(kb4.y); pb = fmaf(qbf[2], f.x, fmaf(qbf[3], f.y, pb));
            f = bf2x(kb4.z); pb = fmaf(qbf[4], f.x, fmaf(qbf[5], f.y, pb));
            f = bf2x(kb4.w); pb = fmaf(qbf[6], f.x, fmaf(qbf[7], f.y, pb));
        }
#pragma unroll
        for (int off = 1; off <= 8; off <<= 1) {
            pa += __shfl_xor(pa, off, 64);
            pb += __shfl_xor(pb, off, 64);
        }
        pa *= scale; pb *= scale;
        if (sub == 0 && v) {
            s2[i] = make_float2(pa, pb);
            float mn = fmaxf(ma, pa);
            da = da * __expf(ma - mn) + __expf(pa - mn);
            ma = mn;
            mn = fmaxf(mb, pb);
            db = db * __expf(mb - mn) + __expf(pb - mn);
            mb = mn;
        }
    }
    // merge online-softmax state across lanes (non-leaders hold neutral)
#pragma unroll
    for (int off = 1; off < 64; off <<= 1) {
        float m2 = __shfl_xor(ma, off, 64), d2 = __shfl_xor(da, off, 64);
        float mn = fmaxf(ma, m2);
        da = da * __expf(ma - mn) + d2 * __expf(m2 - mn);
        ma = mn;
        m2 = __shfl_xor(mb, off, 64); d2 = __shfl_xor(db, off, 64);
        mn = fmaxf(mb, m2);
        db = db * __expf(mb - mn) + d2 * __expf(m2 - mn);
        mb = mn;
    }
    if (lane == 0)
        params[n] = make_float4(ma, (da > 0.f) ? 1.f / da : 0.f,
                                mb, (db > 0.f) ? 1.f / db : 0.f);
}

// ---------- Gather-aggregate: one wave per node, x4 unroll, merged twxw ----------
__global__ __launch_bounds__(256) void node_gather(
    const unsigned short* __restrict__ twxw,
    const int* __restrict__ csr_col, const int* __restrict__ offs,
    const float2* __restrict__ s2, const float4* __restrict__ params,
    float* __restrict__ out_x, float* __restrict__ out_t, int N)
{
    const int n = blockIdx.x * 4 + (threadIdx.x >> 6);
    if (n >= N) return;
    const int lane = threadIdx.x & 63;
    const int s = offs[n], end = offs[n + 1];
    const float4 prm = params[n];

    float at0 = 0.f, at1 = 0.f, ax0 = 0.f, ax1 = 0.f;
    for (int i0 = s; i0 < end; i0 += 4) {
        int cc[4]; float2 sc[4]; uint2 gv[4];
#pragma unroll
        for (int j = 0; j < 4; j++) {
            int i = i0 + j;
            bool v = i < end;
            cc[j] = csr_col[v ? i : s];
            sc[j] = v ? s2[i] : make_float2(-1e30f, -1e30f);
        }
#pragma unroll
        for (int j = 0; j < 4; j++)
            gv[j] = *(const uint2*)(twxw + (size_t)cc[j] * 256 + lane * 4);
#pragma unroll
        for (int j = 0; j < 4; j++) {
            float wa = __expf(sc[j].x - prm.x) * prm.y;
            float wb = __expf(sc[j].y - prm.z) * prm.w;
            float2 tf = bf2x(gv[j].x);
            float2 xf = bf2x(gv[j].y);
            at0 = fmaf(wa, tf.x, at0); at1 = fmaf(wa, tf.y, at1);
            ax0 = fmaf(wb, xf.x, ax0); ax1 = fmaf(wb, xf.y, ax1);
        }
    }
    *(float2*)(out_x + (size_t)n * 128 + lane * 2) = make_float2(ax0, ax1);
    *(float2*)(out_t + (size_t)n * 128 + lane * 2) = make_float2(at0, at1);
}

extern "C" void kernel_launch(void* const* d_in, const int* in_sizes, int n_in,
                              void* d_out, int out_size, void* d_ws, size_t ws_size,
                              hipStream_t stream) {
    const float* x    = (const float*)d_in[0];
    const float* t    = (const float*)d_in[1];
    const int*   ei   = (const int*)d_in[2];
    const float* W_x  = (const float*)d_in[3];
    const float* W_t  = (const float*)d_in[4];
    const float* Qa_w = (const float*)d_in[5];
    const float* Qa_b = (const float*)d_in[6];
    const float* Ka_w = (const float*)d_in[7];
    const float* Ka_b = (const float*)d_in[8];
    const float* Qb_w = (const float*)d_in[9];
    const float* Qb_b = (const float*)d_in[10];
    const float* Kb_w = (const float*)d_in[11];
    const float* Kb_b = (const float*)d_in[12];

    const int N = in_sizes[0] / 128;
    const int E = in_sizes[2] / 2;
    const int* row = ei;
    const int* col = ei + E;

    char* ws = (char*)d_ws;
    size_t off = 0;
    auto carve = [&](size_t bytes) -> void* {
        void* p = ws + off;
        off += (bytes + 255) & ~(size_t)255;
        return p;
    };
    unsigned short* qa   = (unsigned short*)carve((size_t)N * 128 * 2);
    unsigned short* qb   = (unsigned short*)carve((size_t)N * 128 * 2);
    unsigned short* kab  = (unsigned short*)carve((size_t)N * 256 * 2);
    unsigned short* twxw = (unsigned short*)carve((size_t)N * 256 * 2);
    float2* s2    = (float2*)carve((size_t)E * 8);
    float4* prm   = (float4*)carve((size_t)N * 16);
    int* deg      = (int*)carve((size_t)N * 4);
    int* cursor   = (int*)carve((size_t)N * 4);
    int* offs     = (int*)carve((size_t)(N + 1) * 4);
    int* csr_col  = (int*)carve((size_t)E * 4);
    const int nscan = (N + SCAN_CHUNK - 1) / SCAN_CHUNK;
    int* partial  = (int*)carve((size_t)nscan * 4);
    unsigned short* Wbf = (unsigned short*)carve((size_t)6 * 16384 * 2);

    hipMemsetAsync(deg, 0, (size_t)N * 4, stream);

    dim3 b256(256);
    // weight order: [Qa_w, Ka_w, W_t, Qb_w, Kb_w, W_x]
    convert_w<<<dim3(96), b256, 0, stream>>>(Qa_w, Ka_w, W_t, Qb_w, Kb_w, W_x, Wbf);

    const int pgrid = (N + 63) / 64;
    proj_mfma<<<dim3(pgrid), b256, 0, stream>>>(
        t, N, Wbf + 0 * 16384, Qa_b, qa,
        Wbf + 1 * 16384, Ka_b, kab, 0,
        Wbf + 2 * 16384, twxw, 0);
    proj_mfma<<<dim3(pgrid), b256, 0, stream>>>(
        x, N, Wbf + 3 * 16384, Qb_b, qb,
        Wbf + 4 * 16384, Kb_b, kab, 8,
        Wbf + 5 * 16384, twxw, 2);

    hist_k<<<dim3((E + 255) / 256), b256, 0, stream>>>(row, deg, E);
    scan_partial<<<dim3(nscan), b256, 0, stream>>>(deg, partial, N);
    scan_base<<<dim3(1), dim3(64), 0, stream>>>(partial, nscan, offs, N);
    scan_final<<<dim3(nscan), b256, 0, stream>>>(deg, partial, offs, cursor, N);
    scatter_k<<<dim3((E + 255) / 256), b256, 0, stream>>>(row, col, cursor, csr_col, E);

    const int ngrid = (N + 3) / 4;
    edge_scores_csr<<<dim3(ngrid), b256, 0, stream>>>(qa, qb, kab, csr_col, offs, s2, prm, N);

    float* out_x = (float*)d_out;
    float* out_t = out_x + (size_t)N * 128;
    node_gather<<<dim3(ngrid), b256, 0, stream>>>(twxw, csr_col, offs, s2, prm, out_x, out_t, N);
}

// Round 5
// 342.590 us; speedup vs baseline: 1.6506x; 1.0722x over previous
//
#include <hip/hip_runtime.h>

// ---------- bf16 helpers ----------
__device__ __forceinline__ unsigned short f2bf(float f) {
    unsigned int x = __float_as_uint(f);
    x += 0x7fffu + ((x >> 16) & 1u);
    return (unsigned short)(x >> 16);
}
__device__ __forceinline__ float2 bf2x(unsigned int u) {
    float2 r;
    r.x = __uint_as_float(u << 16);
    r.y = __uint_as_float(u & 0xffff0000u);
    return r;
}

typedef __attribute__((ext_vector_type(8))) short frag8;   // 8 bf16
typedef __attribute__((ext_vector_type(4))) float fragf4;  // 4 fp32 acc

// ---------- convert 6 weight matrices [128x128] fp32 -> bf16 ----------
// order: [Qa, Ka, Wt, Qb, Kb, Wx]
__global__ __launch_bounds__(256) void convert_w(
    const float* __restrict__ s0, const float* __restrict__ s1,
    const float* __restrict__ s2, const float* __restrict__ s3,
    const float* __restrict__ s4, const float* __restrict__ s5,
    unsigned short* __restrict__ dst)
{
    int id = blockIdx.x * 256 + threadIdx.x;
    int m = id >> 12;
    int i = (id & 4095) * 4;
    const float* s = (m == 0) ? s0 : (m == 1) ? s1 : (m == 2) ? s2
                   : (m == 3) ? s3 : (m == 4) ? s4 : s5;
    float4 v = *(const float4*)(s + i);
    ushort4 u;
    u.x = f2bf(v.x); u.y = f2bf(v.y); u.z = f2bf(v.z); u.w = f2bf(v.w);
    *(ushort4*)(dst + m * 16384 + i) = u;
}

// ---------- Fused MFMA projection: 64 rows x both inputs x 6 matrices ----------
// Outputs (all via LDS-staged coalesced stores):
//   qa, qb : plain [N][128]
//   kab    : [N][256]: chunk q (16 ushorts) = { ka dims 8q..8q+8, kb dims 8q..8q+8 }
//   twxw   : [N][256]: pos 4p..4p+3 = { tw(2p), tw(2p+1), xw(2p), xw(2p+1) }
#define LSTRQ 136   // LDS row stride (ushorts) for 128-ushort rows
#define LSTRK 264   // LDS row stride (ushorts) for 256-ushort rows
__global__ __launch_bounds__(256) void proj_mfma(
    const float* __restrict__ in_t, const float* __restrict__ in_x, int N,
    const unsigned short* __restrict__ Wbf,
    const float* __restrict__ Qa_b, const float* __restrict__ Ka_b,
    const float* __restrict__ Qb_b, const float* __restrict__ Kb_b,
    unsigned short* __restrict__ qa, unsigned short* __restrict__ qb,
    unsigned short* __restrict__ kab, unsigned short* __restrict__ twxw)
{
    __shared__ __align__(16) unsigned short tile[64 * LSTRK];   // 33792 B

    const int tid = threadIdx.x;
    const int wave = tid >> 6;
    const int lane = tid & 63;
    const int li = lane & 15, quad = lane >> 4;
    const int r0 = blockIdx.x * 64;
    const int r = r0 + wave * 16 + li;
    const bool rv = r < N;
    const int nrows = min(64, N - r0);
    const int lrow = wave * 16 + li;

    // ---- load both inputs' row fragments (fp32 -> bf16 in regs) ----
    frag8 bt[4], bx[4];
    {
        const float* st = in_t + (size_t)r * 128 + quad * 8;
        const float* sx = in_x + (size_t)r * 128 + quad * 8;
#pragma unroll
        for (int ks = 0; ks < 4; ks++) {
            float4 lo = make_float4(0.f,0.f,0.f,0.f), hi = lo;
            float4 lo2 = lo, hi2 = lo;
            if (rv) {
                lo  = *(const float4*)(st + ks * 32);
                hi  = *(const float4*)(st + ks * 32 + 4);
                lo2 = *(const float4*)(sx + ks * 32);
                hi2 = *(const float4*)(sx + ks * 32 + 4);
            }
            frag8 f;
            f[0]=(short)f2bf(lo.x); f[1]=(short)f2bf(lo.y);
            f[2]=(short)f2bf(lo.z); f[3]=(short)f2bf(lo.w);
            f[4]=(short)f2bf(hi.x); f[5]=(short)f2bf(hi.y);
            f[6]=(short)f2bf(hi.z); f[7]=(short)f2bf(hi.w);
            bt[ks] = f;
            f[0]=(short)f2bf(lo2.x); f[1]=(short)f2bf(lo2.y);
            f[2]=(short)f2bf(lo2.z); f[3]=(short)f2bf(lo2.w);
            f[4]=(short)f2bf(hi2.x); f[5]=(short)f2bf(hi2.y);
            f[6]=(short)f2bf(hi2.z); f[7]=(short)f2bf(hi2.w);
            bx[ks] = f;
        }
    }

    fragf4 acc[8];
    auto compute = [&](const unsigned short* Wb, const frag8* bf) {
#pragma unroll
        for (int ct = 0; ct < 8; ct++) acc[ct] = (fragf4){0.f,0.f,0.f,0.f};
#pragma unroll
        for (int ct = 0; ct < 8; ct++) {
            const unsigned short* wp = Wb + (size_t)(ct * 16 + li) * 128 + quad * 8;
#pragma unroll
            for (int ks = 0; ks < 4; ks++) {
                frag8 af = *(const frag8*)(wp + ks * 32);
                acc[ct] = __builtin_amdgcn_mfma_f32_16x16x32_bf16(af, bf[ks], acc[ct], 0, 0, 0);
            }
        }
    };
    auto biased = [&](int ct, const float* bias) -> ushort4 {
        const int c = ct * 16 + quad * 4;
        float4 bv = make_float4(0.f,0.f,0.f,0.f);
        if (bias) bv = *(const float4*)(bias + c);
        ushort4 u;
        u.x = f2bf(acc[ct][0] + bv.x);
        u.y = f2bf(acc[ct][1] + bv.y);
        u.z = f2bf(acc[ct][2] + bv.z);
        u.w = f2bf(acc[ct][3] + bv.w);
        return u;
    };
    auto readout128 = [&](unsigned short* dst) {      // 64 x 128 ushorts
#pragma unroll
        for (int it = 0; it < 4; it++) {
            int chunk = it * 256 + tid;
            int row = chunk >> 4, off = (chunk & 15) * 8;
            if (row < nrows) {
                uint4 v = *(const uint4*)&tile[row * LSTRQ + off];
                *(uint4*)(dst + (size_t)(r0 + row) * 128 + off) = v;
            }
        }
    };
    auto readout256 = [&](unsigned short* dst) {      // 64 x 256 ushorts
#pragma unroll
        for (int it = 0; it < 8; it++) {
            int chunk = it * 256 + tid;
            int row = chunk >> 5, off = (chunk & 31) * 8;
            if (row < nrows) {
                uint4 v = *(const uint4*)&tile[row * LSTRK + off];
                *(uint4*)(dst + (size_t)(r0 + row) * 256 + off) = v;
            }
        }
    };

    // ---- Qa (t) ----
    compute(Wbf + 0 * 16384, bt);
#pragma unroll
    for (int ct = 0; ct < 8; ct++) {
        ushort4 u = biased(ct, Qa_b);
        *(ushort4*)&tile[lrow * LSTRQ + ct * 16 + quad * 4] = u;
    }
    __syncthreads();
    readout128(qa);
    __syncthreads();

    // ---- Qb (x) ----
    compute(Wbf + 3 * 16384, bx);
#pragma unroll
    for (int ct = 0; ct < 8; ct++) {
        ushort4 u = biased(ct, Qb_b);
        *(ushort4*)&tile[lrow * LSTRQ + ct * 16 + quad * 4] = u;
    }
    __syncthreads();
    readout128(qb);
    __syncthreads();

    // ---- Ka (t) + Kb (x) -> kab ----
    compute(Wbf + 1 * 16384, bt);
#pragma unroll
    for (int ct = 0; ct < 8; ct++) {
        ushort4 u = biased(ct, Ka_b);
        const int c = ct * 16 + quad * 4;
        *(ushort4*)&tile[lrow * LSTRK + ((c >> 3) << 4) + (c & 7)] = u;
    }
    compute(Wbf + 4 * 16384, bx);
#pragma unroll
    for (int ct = 0; ct < 8; ct++) {
        ushort4 u = biased(ct, Kb_b);
        const int c = ct * 16 + quad * 4;
        *(ushort4*)&tile[lrow * LSTRK + ((c >> 3) << 4) + 8 + (c & 7)] = u;
    }
    __syncthreads();
    readout256(kab);
    __syncthreads();

    // ---- Wt (t) + Wx (x) -> twxw ----
    compute(Wbf + 2 * 16384, bt);
#pragma unroll
    for (int ct = 0; ct < 8; ct++) {
        ushort4 u = biased(ct, nullptr);
        const int c = ct * 16 + quad * 4;
        ushort2 p0; p0.x = u.x; p0.y = u.y;
        ushort2 p1; p1.x = u.z; p1.y = u.w;
        *(ushort2*)&tile[lrow * LSTRK + c * 2] = p0;
        *(ushort2*)&tile[lrow * LSTRK + c * 2 + 4] = p1;
    }
    compute(Wbf + 5 * 16384, bx);
#pragma unroll
    for (int ct = 0; ct < 8; ct++) {
        ushort4 u = biased(ct, nullptr);
        const int c = ct * 16 + quad * 4;
        ushort2 p0; p0.x = u.x; p0.y = u.y;
        ushort2 p1; p1.x = u.z; p1.y = u.w;
        *(ushort2*)&tile[lrow * LSTRK + c * 2 + 2] = p0;
        *(ushort2*)&tile[lrow * LSTRK + c * 2 + 6] = p1;
    }
    __syncthreads();
    readout256(twxw);
}

// ---------- CSR build ----------
__global__ __launch_bounds__(256) void hist_k(const int* __restrict__ row, int* __restrict__ deg, int E) {
    int e = blockIdx.x * 256 + threadIdx.x;
    if (e < E) atomicAdd(&deg[row[e]], 1);
}

#define SCAN_CHUNK 2048

__device__ __forceinline__ int wave_incl_scan(int v, int lane) {
#pragma unroll
    for (int d = 1; d < 64; d <<= 1) {
        int u = __shfl_up(v, d, 64);
        if (lane >= d) v += u;
    }
    return v;
}

__global__ __launch_bounds__(256) void scan_partial(const int* __restrict__ deg,
                                                    int* __restrict__ partial, int N) {
    const int tid = threadIdx.x;
    const int base = blockIdx.x * SCAN_CHUNK + tid * 8;
    int s = 0;
#pragma unroll
    for (int j = 0; j < 8; j++) {
        int i = base + j;
        s += (i < N) ? deg[i] : 0;
    }
    const int lane = tid & 63;
    s = wave_incl_scan(s, lane);
    __shared__ int wsum[4];
    if (lane == 63) wsum[tid >> 6] = s;
    __syncthreads();
    if (tid == 0) partial[blockIdx.x] = wsum[0] + wsum[1] + wsum[2] + wsum[3];
}

__global__ __launch_bounds__(64) void scan_base(int* __restrict__ partial, int nb,
                                                int* __restrict__ offs, int N) {
    const int lane = threadIdx.x;
    int v = (lane < nb) ? partial[lane] : 0;
    int inc = wave_incl_scan(v, lane);
    if (lane < nb) partial[lane] = inc - v;
    if (lane == 63) offs[N] = inc;
}

__global__ __launch_bounds__(256) void scan_final(const int* __restrict__ deg,
                                                  const int* __restrict__ partial,
                                                  int* __restrict__ offs,
                                                  int* __restrict__ cursor, int N) {
    const int tid = threadIdx.x;
    const int lane = tid & 63;
    const int wv = tid >> 6;
    const int base = blockIdx.x * SCAN_CHUNK + tid * 8;
    int v[8];
    int s = 0;
#pragma unroll
    for (int j = 0; j < 8; j++) {
        int i = base + j;
        v[j] = (i < N) ? deg[i] : 0;
        s += v[j];
    }
    int incl = wave_incl_scan(s, lane);
    __shared__ int wsum[4];
    if (lane == 63) wsum[wv] = incl;
    __syncthreads();
    int wbase = 0;
#pragma unroll
    for (int w = 0; w < 4; w++) wbase += (w < wv) ? wsum[w] : 0;
    int run = partial[blockIdx.x] + wbase + incl - s;
#pragma unroll
    for (int j = 0; j < 8; j++) {
        int i = base + j;
        if (i < N) { offs[i] = run; cursor[i] = run; }
        run += v[j];
    }
}

__global__ __launch_bounds__(256) void scatter_k(const int* __restrict__ row,
                                                 const int* __restrict__ col,
                                                 int* __restrict__ cursor,
                                                 int* __restrict__ csr_col, int E) {
    int e = blockIdx.x * 256 + threadIdx.x;
    if (e < E) {
        int p = atomicAdd(&cursor[row[e]], 1);
        csr_col[p] = col[e];
    }
}

// ---------- Fused edge scores + online softmax + V-aggregation ----------
// One wave per dest node. 4 edges/iter: 16-lane groups compute K-dots; all 64
// lanes gather V (twxw) and maintain flash-style rescaled accumulators.
__global__ __launch_bounds__(256) void edge_fused(
    const unsigned short* __restrict__ qa, const unsigned short* __restrict__ qb,
    const unsigned short* __restrict__ kab, const unsigned short* __restrict__ twxw,
    const int* __restrict__ csr_col, const int* __restrict__ offs,
    float* __restrict__ out_x, float* __restrict__ out_t, int N)
{
    const int n = blockIdx.x * 4 + (threadIdx.x >> 6);
    if (n >= N) return;
    const int lane = threadIdx.x & 63;
    const int g = lane >> 4, sub = lane & 15;
    const int s = offs[n], end = offs[n + 1];

    float qaf[8], qbf[8];
    {
        uint4 a = *(const uint4*)(qa + (size_t)n * 128 + sub * 8);
        uint4 b = *(const uint4*)(qb + (size_t)n * 128 + sub * 8);
        float2 f;
        f = bf2x(a.x); qaf[0] = f.x; qaf[1] = f.y;
        f = bf2x(a.y); qaf[2] = f.x; qaf[3] = f.y;
        f = bf2x(a.z); qaf[4] = f.x; qaf[5] = f.y;
        f = bf2x(a.w); qaf[6] = f.x; qaf[7] = f.y;
        f = bf2x(b.x); qbf[0] = f.x; qbf[1] = f.y;
        f = bf2x(b.y); qbf[2] = f.x; qbf[3] = f.y;
        f = bf2x(b.z); qbf[4] = f.x; qbf[5] = f.y;
        f = bf2x(b.w); qbf[6] = f.x; qbf[7] = f.y;
    }

    const float scale = 0.08838834764831845f;  // 1/sqrt(128)
    float m_a = -1e30f, d_a = 0.f, m_b = -1e30f, d_b = 0.f;
    float at0 = 0.f, at1 = 0.f, ax0 = 0.f, ax1 = 0.f;

    for (int i0 = s; i0 < end; i0 += 4) {
        const int i = i0 + g;
        const int c = csr_col[(i < end) ? i : (end - 1)];

        // broadcast all 4 col ids, issue all V gathers early
        int cj[4];
#pragma unroll
        for (int j = 0; j < 4; j++) cj[j] = __shfl(c, j * 16, 64);
        uint2 gv[4];
#pragma unroll
        for (int j = 0; j < 4; j++)
            gv[j] = *(const uint2*)(twxw + (size_t)cj[j] * 256 + lane * 4);

        // K gather + dot (own group's edge)
        const unsigned short* kp = kab + (size_t)c * 256 + sub * 16;
        uint4 ka4 = *(const uint4*)kp;
        uint4 kb4 = *(const uint4*)(kp + 8);
        float pa = 0.f, pb = 0.f;
        {
            float2 f;
            f = bf2x(ka4.x); pa = fmaf(qaf[0], f.x, fmaf(qaf[1], f.y, pa));
            f = bf2x(ka4.y); pa = fmaf(qaf[2], f.x, fmaf(qaf[3], f.y, pa));
            f = bf2x(ka4.z); pa = fmaf(qaf[4], f.x, fmaf(qaf[5], f.y, pa));
            f = bf2x(ka4.w); pa = fmaf(qaf[6], f.x, fmaf(qaf[7], f.y, pa));
            f = bf2x(kb4.x); pb = fmaf(qbf[0], f.x, fmaf(qbf[1], f.y, pb));
            f = bf2x(kb4.y); pb = fmaf(qbf[2], f.x, fmaf(qbf[3], f.y, pb));
            f = bf2x(kb4.z); pb = fmaf(qbf[4], f.x, fmaf(qbf[5], f.y, pb));
            f = bf2x(kb4.w); pb = fmaf(qbf[6], f.x, fmaf(qbf[7], f.y, pb));
        }
#pragma unroll
        for (int off = 1; off <= 8; off <<= 1) {
            pa += __shfl_xor(pa, off, 64);
            pb += __shfl_xor(pb, off, 64);
        }
        pa *= scale; pb *= scale;

        const int nv = min(4, end - i0);   // wave-uniform
#pragma unroll
        for (int j = 0; j < 4; j++) {
            if (j < nv) {
                float pja = __shfl(pa, j * 16, 64);
                float pjb = __shfl(pb, j * 16, 64);
                float2 tf = bf2x(gv[j].x);
                float2 xf = bf2x(gv[j].y);
                float mna = fmaxf(m_a, pja);
                float al = __expf(m_a - mna), wa = __expf(pja - mna);
                d_a = d_a * al + wa; m_a = mna;
                at0 = at0 * al + wa * tf.x;
                at1 = at1 * al + wa * tf.y;
                float mnb = fmaxf(m_b, pjb);
                float bl = __expf(m_b - mnb), wb = __expf(pjb - mnb);
                d_b = d_b * bl + wb; m_b = mnb;
                ax0 = ax0 * bl + wb * xf.x;
                ax1 = ax1 * bl + wb * xf.y;
            }
        }
    }
    const float ra = (d_a > 0.f) ? 1.f / d_a : 0.f;
    const float rb = (d_b > 0.f) ? 1.f / d_b : 0.f;
    *(float2*)(out_t + (size_t)n * 128 + lane * 2) = make_float2(at0 * ra, at1 * ra);
    *(float2*)(out_x + (size_t)n * 128 + lane * 2) = make_float2(ax0 * rb, ax1 * rb);
}

extern "C" void kernel_launch(void* const* d_in, const int* in_sizes, int n_in,
                              void* d_out, int out_size, void* d_ws, size_t ws_size,
                              hipStream_t stream) {
    const float* x    = (const float*)d_in[0];
    const float* t    = (const float*)d_in[1];
    const int*   ei   = (const int*)d_in[2];
    const float* W_x  = (const float*)d_in[3];
    const float* W_t  = (const float*)d_in[4];
    const float* Qa_w = (const float*)d_in[5];
    const float* Qa_b = (const float*)d_in[6];
    const float* Ka_w = (const float*)d_in[7];
    const float* Ka_b = (const float*)d_in[8];
    const float* Qb_w = (const float*)d_in[9];
    const float* Qb_b = (const float*)d_in[10];
    const float* Kb_w = (const float*)d_in[11];
    const float* Kb_b = (const float*)d_in[12];

    const int N = in_sizes[0] / 128;
    const int E = in_sizes[2] / 2;
    const int* row = ei;
    const int* col = ei + E;

    char* ws = (char*)d_ws;
    size_t off = 0;
    auto carve = [&](size_t bytes) -> void* {
        void* p = ws + off;
        off += (bytes + 255) & ~(size_t)255;
        return p;
    };
    unsigned short* qa   = (unsigned short*)carve((size_t)N * 128 * 2);
    unsigned short* qb   = (unsigned short*)carve((size_t)N * 128 * 2);
    unsigned short* kab  = (unsigned short*)carve((size_t)N * 256 * 2);
    unsigned short* twxw = (unsigned short*)carve((size_t)N * 256 * 2);
    int* deg      = (int*)carve((size_t)N * 4);
    int* cursor   = (int*)carve((size_t)N * 4);
    int* offs     = (int*)carve((size_t)(N + 1) * 4);
    int* csr_col  = (int*)carve((size_t)E * 4);
    const int nscan = (N + SCAN_CHUNK - 1) / SCAN_CHUNK;
    int* partial  = (int*)carve((size_t)nscan * 4);
    unsigned short* Wbf = (unsigned short*)carve((size_t)6 * 16384 * 2);

    hipMemsetAsync(deg, 0, (size_t)N * 4, stream);

    dim3 b256(256);
    // weight order: [Qa, Ka, Wt, Qb, Kb, Wx]
    convert_w<<<dim3(96), b256, 0, stream>>>(Qa_w, Ka_w, W_t, Qb_w, Kb_w, W_x, Wbf);

    proj_mfma<<<dim3((N + 63) / 64), b256, 0, stream>>>(
        t, x, N, Wbf, Qa_b, Ka_b, Qb_b, Kb_b, qa, qb, kab, twxw);

    hist_k<<<dim3((E + 255) / 256), b256, 0, stream>>>(row, deg, E);
    scan_partial<<<dim3(nscan), b256, 0, stream>>>(deg, partial, N);
    scan_base<<<dim3(1), dim3(64), 0, stream>>>(partial, nscan, offs, N);
    scan_final<<<dim3(nscan), b256, 0, stream>>>(deg, partial, offs, cursor, N);
    scatter_k<<<dim3((E + 255) / 256), b256, 0, stream>>>(row, col, cursor, csr_col, E);

    float* out_x = (float*)d_out;
    float* out_t = out_x + (size_t)N * 128;
    edge_fused<<<dim3((N + 3) / 4), b256, 0, stream>>>(
        qa, qb, kab, twxw, csr_col, offs, out_x, out_t, N);
}

// Round 6
// 336.583 us; speedup vs baseline: 1.6801x; 1.0178x over previous
//
#include <hip/hip_runtime.h>

// ---------- bf16 helpers ----------
__device__ __forceinline__ unsigned short f2bf(float f) {
    unsigned int x = __float_as_uint(f);
    x += 0x7fffu + ((x >> 16) & 1u);
    return (unsigned short)(x >> 16);
}
__device__ __forceinline__ float2 bf2x(unsigned int u) {
    float2 r;
    r.x = __uint_as_float(u << 16);
    r.y = __uint_as_float(u & 0xffff0000u);
    return r;
}

typedef __attribute__((ext_vector_type(8))) short frag8;   // 8 bf16
typedef __attribute__((ext_vector_type(4))) float fragf4;  // 4 fp32 acc

// ---------- convert 6 weight matrices [128x128] fp32 -> bf16 ----------
// order: [Qa, Ka, Wt, Qb, Kb, Wx]
__global__ __launch_bounds__(256) void convert_w(
    const float* __restrict__ s0, const float* __restrict__ s1,
    const float* __restrict__ s2, const float* __restrict__ s3,
    const float* __restrict__ s4, const float* __restrict__ s5,
    unsigned short* __restrict__ dst)
{
    int id = blockIdx.x * 256 + threadIdx.x;
    int m = id >> 12;
    int i = (id & 4095) * 4;
    const float* s = (m == 0) ? s0 : (m == 1) ? s1 : (m == 2) ? s2
                   : (m == 3) ? s3 : (m == 4) ? s4 : s5;
    float4 v = *(const float4*)(s + i);
    ushort4 u;
    u.x = f2bf(v.x); u.y = f2bf(v.y); u.z = f2bf(v.z); u.w = f2bf(v.w);
    *(ushort4*)(dst + m * 16384 + i) = u;
}

// ---------- Barrier-free MFMA projection ----------
// One WAVE owns one 16-row tile and runs 6 independent phases (matrix x input),
// each: 32 MFMA -> private LDS buffer (double-buffered) -> coalesced stores.
// Output layouts (concatenated halves):
//   qa, qb : [N][128]
//   kab    : [N][256] = [ ka(128) | kb(128) ]
//   twxw   : [N][256] = [ tw(128) | xw(128) ]
#define LROW 136   // LDS row stride in ushorts (2-way bank alias only)
__global__ __launch_bounds__(256) void proj_mfma(
    const float* __restrict__ in_t, const float* __restrict__ in_x, int N,
    const unsigned short* __restrict__ Wbf,
    const float* __restrict__ Qa_b, const float* __restrict__ Ka_b,
    const float* __restrict__ Qb_b, const float* __restrict__ Kb_b,
    unsigned short* __restrict__ qa, unsigned short* __restrict__ qb,
    unsigned short* __restrict__ kab, unsigned short* __restrict__ twxw)
{
    __shared__ __align__(16) unsigned short tile[4][2][16 * LROW];  // 34816 B

    const int wave = threadIdx.x >> 6;
    const int lane = threadIdx.x & 63;
    const int li = lane & 15, quad = lane >> 4;
    const int sub = lane & 15;          // alias for readback
    const int r0 = (blockIdx.x * 4 + wave) * 16;
    if (r0 >= N) return;
    const int r = r0 + li;
    const bool rv = r < N;

    // ---- load both inputs' row fragments (fp32 -> bf16 in regs), once ----
    frag8 bt[4], bx[4];
    {
        const float* st = in_t + (size_t)r * 128 + quad * 8;
        const float* sx = in_x + (size_t)r * 128 + quad * 8;
#pragma unroll
        for (int ks = 0; ks < 4; ks++) {
            float4 lo = make_float4(0.f,0.f,0.f,0.f), hi = lo;
            float4 lo2 = lo, hi2 = lo;
            if (rv) {
                lo  = *(const float4*)(st + ks * 32);
                hi  = *(const float4*)(st + ks * 32 + 4);
                lo2 = *(const float4*)(sx + ks * 32);
                hi2 = *(const float4*)(sx + ks * 32 + 4);
            }
            frag8 f;
            f[0]=(short)f2bf(lo.x); f[1]=(short)f2bf(lo.y);
            f[2]=(short)f2bf(lo.z); f[3]=(short)f2bf(lo.w);
            f[4]=(short)f2bf(hi.x); f[5]=(short)f2bf(hi.y);
            f[6]=(short)f2bf(hi.z); f[7]=(short)f2bf(hi.w);
            bt[ks] = f;
            f[0]=(short)f2bf(lo2.x); f[1]=(short)f2bf(lo2.y);
            f[2]=(short)f2bf(lo2.z); f[3]=(short)f2bf(lo2.w);
            f[4]=(short)f2bf(hi2.x); f[5]=(short)f2bf(hi2.y);
            f[6]=(short)f2bf(hi2.z); f[7]=(short)f2bf(hi2.w);
            bx[ks] = f;
        }
    }

    int buf = 0;
    auto phase = [&](const unsigned short* Wb, const frag8* bf, const float* bias,
                     unsigned short* dst, int rstride, int coff) {
        fragf4 acc[8];
#pragma unroll
        for (int ct = 0; ct < 8; ct++) acc[ct] = (fragf4){0.f,0.f,0.f,0.f};
#pragma unroll
        for (int ct = 0; ct < 8; ct++) {
            const unsigned short* wp = Wb + (size_t)(ct * 16 + li) * 128 + quad * 8;
#pragma unroll
            for (int ks = 0; ks < 4; ks++) {
                frag8 af = *(const frag8*)(wp + ks * 32);
                acc[ct] = __builtin_amdgcn_mfma_f32_16x16x32_bf16(af, bf[ks], acc[ct], 0, 0, 0);
            }
        }
        // D-layout: lane(li,quad) holds node row li, channels ct*16+quad*4..+3
        unsigned short* lt = &tile[wave][buf][0];
#pragma unroll
        for (int ct = 0; ct < 8; ct++) {
            const int c = ct * 16 + quad * 4;
            float4 bv = make_float4(0.f,0.f,0.f,0.f);
            if (bias) bv = *(const float4*)(bias + c);
            ushort4 u;
            u.x = f2bf(acc[ct][0] + bv.x);
            u.y = f2bf(acc[ct][1] + bv.y);
            u.z = f2bf(acc[ct][2] + bv.z);
            u.w = f2bf(acc[ct][3] + bv.w);
            *(ushort4*)&lt[li * LROW + c] = u;
        }
        // wave-internal readback (in-order DS pipe; no barrier needed)
#pragma unroll
        for (int it = 0; it < 4; it++) {
            const int rr = it * 4 + quad;
            if (r0 + rr < N) {
                uint4 v = *(const uint4*)&lt[rr * LROW + sub * 8];
                *(uint4*)(dst + (size_t)(r0 + rr) * rstride + coff + sub * 8) = v;
            }
        }
        buf ^= 1;
    };

    phase(Wbf + 0 * 16384, bt, Qa_b, qa,   128, 0);
    phase(Wbf + 3 * 16384, bx, Qb_b, qb,   128, 0);
    phase(Wbf + 1 * 16384, bt, Ka_b, kab,  256, 0);
    phase(Wbf + 4 * 16384, bx, Kb_b, kab,  256, 128);
    phase(Wbf + 2 * 16384, bt, nullptr, twxw, 256, 0);
    phase(Wbf + 5 * 16384, bx, nullptr, twxw, 256, 128);
}

// ---------- CSR build ----------
__global__ __launch_bounds__(256) void hist_k(const int* __restrict__ row, int* __restrict__ deg, int E) {
    int e = blockIdx.x * 256 + threadIdx.x;
    if (e < E) atomicAdd(&deg[row[e]], 1);
}

#define SCAN_CHUNK 2048

__device__ __forceinline__ int wave_incl_scan(int v, int lane) {
#pragma unroll
    for (int d = 1; d < 64; d <<= 1) {
        int u = __shfl_up(v, d, 64);
        if (lane >= d) v += u;
    }
    return v;
}

__global__ __launch_bounds__(256) void scan_partial(const int* __restrict__ deg,
                                                    int* __restrict__ partial, int N) {
    const int tid = threadIdx.x;
    const int base = blockIdx.x * SCAN_CHUNK + tid * 8;
    int s = 0;
#pragma unroll
    for (int j = 0; j < 8; j++) {
        int i = base + j;
        s += (i < N) ? deg[i] : 0;
    }
    const int lane = tid & 63;
    s = wave_incl_scan(s, lane);
    __shared__ int wsum[4];
    if (lane == 63) wsum[tid >> 6] = s;
    __syncthreads();
    if (tid == 0) partial[blockIdx.x] = wsum[0] + wsum[1] + wsum[2] + wsum[3];
}

__global__ __launch_bounds__(64) void scan_base(int* __restrict__ partial, int nb,
                                                int* __restrict__ offs, int N) {
    const int lane = threadIdx.x;
    int v = (lane < nb) ? partial[lane] : 0;
    int inc = wave_incl_scan(v, lane);
    if (lane < nb) partial[lane] = inc - v;
    if (lane == 63) offs[N] = inc;
}

__global__ __launch_bounds__(256) void scan_final(const int* __restrict__ deg,
                                                  const int* __restrict__ partial,
                                                  int* __restrict__ offs,
                                                  int* __restrict__ cursor, int N) {
    const int tid = threadIdx.x;
    const int lane = tid & 63;
    const int wv = tid >> 6;
    const int base = blockIdx.x * SCAN_CHUNK + tid * 8;
    int v[8];
    int s = 0;
#pragma unroll
    for (int j = 0; j < 8; j++) {
        int i = base + j;
        v[j] = (i < N) ? deg[i] : 0;
        s += v[j];
    }
    int incl = wave_incl_scan(s, lane);
    __shared__ int wsum[4];
    if (lane == 63) wsum[wv] = incl;
    __syncthreads();
    int wbase = 0;
#pragma unroll
    for (int w = 0; w < 4; w++) wbase += (w < wv) ? wsum[w] : 0;
    int run = partial[blockIdx.x] + wbase + incl - s;
#pragma unroll
    for (int j = 0; j < 8; j++) {
        int i = base + j;
        if (i < N) { offs[i] = run; cursor[i] = run; }
        run += v[j];
    }
}

__global__ __launch_bounds__(256) void scatter_k(const int* __restrict__ row,
                                                 const int* __restrict__ col,
                                                 int* __restrict__ cursor,
                                                 int* __restrict__ csr_col, int E) {
    int e = blockIdx.x * 256 + threadIdx.x;
    if (e < E) {
        int p = atomicAdd(&cursor[row[e]], 1);
        csr_col[p] = col[e];
    }
}

// ---------- Fused edge scores + online softmax + V-aggregation ----------
__global__ __launch_bounds__(256) void edge_fused(
    const unsigned short* __restrict__ qa, const unsigned short* __restrict__ qb,
    const unsigned short* __restrict__ kab, const unsigned short* __restrict__ twxw,
    const int* __restrict__ csr_col, const int* __restrict__ offs,
    float* __restrict__ out_x, float* __restrict__ out_t, int N)
{
    const int n = blockIdx.x * 4 + (threadIdx.x >> 6);
    if (n >= N) return;
    const int lane = threadIdx.x & 63;
    const int g = lane >> 4, sub = lane & 15;
    const int s = offs[n], end = offs[n + 1];

    float qaf[8], qbf[8];
    {
        uint4 a = *(const uint4*)(qa + (size_t)n * 128 + sub * 8);
        uint4 b = *(const uint4*)(qb + (size_t)n * 128 + sub * 8);
        float2 f;
        f = bf2x(a.x); qaf[0] = f.x; qaf[1] = f.y;
        f = bf2x(a.y); qaf[2] = f.x; qaf[3] = f.y;
        f = bf2x(a.z); qaf[4] = f.x; qaf[5] = f.y;
        f = bf2x(a.w); qaf[6] = f.x; qaf[7] = f.y;
        f = bf2x(b.x); qbf[0] = f.x; qbf[1] = f.y;
        f = bf2x(b.y); qbf[2] = f.x; qbf[3] = f.y;
        f = bf2x(b.z); qbf[4] = f.x; qbf[5] = f.y;
        f = bf2x(b.w); qbf[6] = f.x; qbf[7] = f.y;
    }

    const float scale = 0.08838834764831845f;  // 1/sqrt(128)
    float m_a = -1e30f, d_a = 0.f, m_b = -1e30f, d_b = 0.f;
    float at0 = 0.f, at1 = 0.f, ax0 = 0.f, ax1 = 0.f;

    for (int i0 = s; i0 < end; i0 += 4) {
        const int i = i0 + g;
        const int c = csr_col[(i < end) ? i : (end - 1)];

        int cj[4];
#pragma unroll
        for (int j = 0; j < 4; j++) cj[j] = __shfl(c, j * 16, 64);
        unsigned int gvt[4], gvx[4];
#pragma unroll
        for (int j = 0; j < 4; j++) {
            const unsigned short* vp = twxw + (size_t)cj[j] * 256 + lane * 2;
            gvt[j] = *(const unsigned int*)vp;
            gvx[j] = *(const unsigned int*)(vp + 128);
        }

        const unsigned short* kp = kab + (size_t)c * 256 + sub * 8;
        uint4 ka4 = *(const uint4*)kp;
        uint4 kb4 = *(const uint4*)(kp + 128);
        float pa = 0.f, pb = 0.f;
        {
            float2 f;
            f = bf2x(ka4.x); pa = fmaf(qaf[0], f.x, fmaf(qaf[1], f.y, pa));
            f = bf2x(ka4.y); pa = fmaf(qaf[2], f.x, fmaf(qaf[3], f.y, pa));
            f = bf2x(ka4.z); pa = fmaf(qaf[4], f.x, fmaf(qaf[5], f.y, pa));
            f = bf2x(ka4.w); pa = fmaf(qaf[6], f.x, fmaf(qaf[7], f.y, pa));
            f = bf2x(kb4.x); pb = fmaf(qbf[0], f.x, fmaf(qbf[1], f.y, pb));
            f = bf2x(kb4.y); pb = fmaf(qbf[2], f.x, fmaf(qbf[3], f.y, pb));
            f = bf2x(kb4.z); pb = fmaf(qbf[4], f.x, fmaf(qbf[5], f.y, pb));
            f = bf2x(kb4.w); pb = fmaf(qbf[6], f.x, fmaf(qbf[7], f.y, pb));
        }
#pragma unroll
        for (int off = 1; off <= 8; off <<= 1) {
            pa += __shfl_xor(pa, off, 64);
            pb += __shfl_xor(pb, off, 64);
        }
        pa *= scale; pb *= scale;

        const int nv = min(4, end - i0);   // wave-uniform
#pragma unroll
        for (int j = 0; j < 4; j++) {
            if (j < nv) {
                float pja = __shfl(pa, j * 16, 64);
                float pjb = __shfl(pb, j * 16, 64);
                float2 tf = bf2x(gvt[j]);
                float2 xf = bf2x(gvx[j]);
                float mna = fmaxf(m_a, pja);
                float al = __expf(m_a - mna), wa = __expf(pja - mna);
                d_a = d_a * al + wa; m_a = mna;
                at0 = at0 * al + wa * tf.x;
                at1 = at1 * al + wa * tf.y;
                float mnb = fmaxf(m_b, pjb);
                float bl = __expf(m_b - mnb), wb = __expf(pjb - mnb);
                d_b = d_b * bl + wb; m_b = mnb;
                ax0 = ax0 * bl + wb * xf.x;
                ax1 = ax1 * bl + wb * xf.y;
            }
        }
    }
    const float ra = (d_a > 0.f) ? 1.f / d_a : 0.f;
    const float rb = (d_b > 0.f) ? 1.f / d_b : 0.f;
    *(float2*)(out_t + (size_t)n * 128 + lane * 2) = make_float2(at0 * ra, at1 * ra);
    *(float2*)(out_x + (size_t)n * 128 + lane * 2) = make_float2(ax0 * rb, ax1 * rb);
}

extern "C" void kernel_launch(void* const* d_in, const int* in_sizes, int n_in,
                              void* d_out, int out_size, void* d_ws, size_t ws_size,
                              hipStream_t stream) {
    const float* x    = (const float*)d_in[0];
    const float* t    = (const float*)d_in[1];
    const int*   ei   = (const int*)d_in[2];
    const float* W_x  = (const float*)d_in[3];
    const float* W_t  = (const float*)d_in[4];
    const float* Qa_w = (const float*)d_in[5];
    const float* Qa_b = (const float*)d_in[6];
    const float* Ka_w = (const float*)d_in[7];
    const float* Ka_b = (const float*)d_in[8];
    const float* Qb_w = (const float*)d_in[9];
    const float* Qb_b = (const float*)d_in[10];
    const float* Kb_w = (const float*)d_in[11];
    const float* Kb_b = (const float*)d_in[12];

    const int N = in_sizes[0] / 128;
    const int E = in_sizes[2] / 2;
    const int* row = ei;
    const int* col = ei + E;

    char* ws = (char*)d_ws;
    size_t off = 0;
    auto carve = [&](size_t bytes) -> void* {
        void* p = ws + off;
        off += (bytes + 255) & ~(size_t)255;
        return p;
    };
    unsigned short* qa   = (unsigned short*)carve((size_t)N * 128 * 2);
    unsigned short* qb   = (unsigned short*)carve((size_t)N * 128 * 2);
    unsigned short* kab  = (unsigned short*)carve((size_t)N * 256 * 2);
    unsigned short* twxw = (unsigned short*)carve((size_t)N * 256 * 2);
    int* deg      = (int*)carve((size_t)N * 4);
    int* cursor   = (int*)carve((size_t)N * 4);
    int* offs     = (int*)carve((size_t)(N + 1) * 4);
    int* csr_col  = (int*)carve((size_t)E * 4);
    const int nscan = (N + SCAN_CHUNK - 1) / SCAN_CHUNK;
    int* partial  = (int*)carve((size_t)nscan * 4);
    unsigned short* Wbf = (unsigned short*)carve((size_t)6 * 16384 * 2);

    hipMemsetAsync(deg, 0, (size_t)N * 4, stream);

    dim3 b256(256);
    // weight order: [Qa, Ka, Wt, Qb, Kb, Wx]
    convert_w<<<dim3(96), b256, 0, stream>>>(Qa_w, Ka_w, W_t, Qb_w, Kb_w, W_x, Wbf);

    proj_mfma<<<dim3((N + 63) / 64), b256, 0, stream>>>(
        t, x, N, Wbf, Qa_b, Ka_b, Qb_b, Kb_b, qa, qb, kab, twxw);

    hist_k<<<dim3((E + 255) / 256), b256, 0, stream>>>(row, deg, E);
    scan_partial<<<dim3(nscan), b256, 0, stream>>>(deg, partial, N);
    scan_base<<<dim3(1), dim3(64), 0, stream>>>(partial, nscan, offs, N);
    scan_final<<<dim3(nscan), b256, 0, stream>>>(deg, partial, offs, cursor, N);
    scatter_k<<<dim3((E + 255) / 256), b256, 0, stream>>>(row, col, cursor, csr_col, E);

    float* out_x = (float*)d_out;
    float* out_t = out_x + (size_t)N * 128;
    edge_fused<<<dim3((N + 3) / 4), b256, 0, stream>>>(
        qa, qb, kab, twxw, csr_col, offs, out_x, out_t, N);
}